// Round 5
// baseline (993.755 us; speedup 1.0000x reference)
//
#include <hip/hip_runtime.h>
#include <math.h>

#define B_ 16
#define S_ 256
#define T_ 2048
#define D_ 512
#define H_ 8
#define L_ 6
#define FF_ 2048
#define NM_ 80
#define M_ 4096  // B_*S_

typedef float floatx4 __attribute__((ext_vector_type(4)));
typedef __bf16 bf16x8 __attribute__((ext_vector_type(8)));

__device__ __forceinline__ float bf2f(unsigned u) {
    return __uint_as_float((u & 0xffffu) << 16);
}
__device__ __forceinline__ unsigned short f2bf(float f) {
    unsigned u = __float_as_uint(f);
    unsigned r = u + 0x7fffu + ((u >> 16) & 1u);
    return (unsigned short)(r >> 16);
}
__device__ __forceinline__ void gload_lds16(const void* g, void* l) {
    __builtin_amdgcn_global_load_lds(
        (const __attribute__((address_space(1))) void*)g,
        (__attribute__((address_space(3))) void*)l, 16, 0, 0);
}

// ---------------------------------------------------------------------------
// Tiled transpose + f32->bf16: src [Z][K][N] -> dst [Z][N][K] (bf16)
// ---------------------------------------------------------------------------
__global__ __launch_bounds__(256) void transpose_bf16(
    const float* __restrict__ src, unsigned short* __restrict__ dst,
    int K, int N)
{
    __shared__ float tile[32][33];
    const int k0 = blockIdx.y * 32, n0 = blockIdx.x * 32;
    src += (size_t)blockIdx.z * K * N;
    dst += (size_t)blockIdx.z * K * N;
    const int tx = threadIdx.x, ty = threadIdx.y;
#pragma unroll
    for (int i = 0; i < 32; i += 8)
        tile[ty + i][tx] = src[(size_t)(k0 + ty + i) * N + n0 + tx];
    __syncthreads();
#pragma unroll
    for (int i = 0; i < 32; i += 8)
        dst[(size_t)(n0 + ty + i) * K + k0 + tx] = f2bf(tile[tx][ty + i]);
}

// Transpose with column padding: src [K][Ns] f32 -> dst [Np][K] bf16, rows>=Ns zero
__global__ __launch_bounds__(256) void transpose_pad_bf16(
    const float* __restrict__ src, unsigned short* __restrict__ dst,
    int K, int Ns)
{
    __shared__ float tile[32][33];
    const int k0 = blockIdx.y * 32, n0 = blockIdx.x * 32;
    const int tx = threadIdx.x, ty = threadIdx.y;
#pragma unroll
    for (int i = 0; i < 32; i += 8) {
        int n = n0 + tx;
        tile[ty + i][tx] = (n < Ns) ? src[(size_t)(k0 + ty + i) * Ns + n] : 0.f;
    }
    __syncthreads();
#pragma unroll
    for (int i = 0; i < 32; i += 8)
        dst[(size_t)(n0 + ty + i) * K + k0 + tx] = f2bf(tile[tx][ty + i]);
}

// ---------------------------------------------------------------------------
// Embedding + positional encoding -> bf16 x
// ---------------------------------------------------------------------------
__global__ __launch_bounds__(128) void embed_bf16(
    const int* __restrict__ ids, const float* __restrict__ emb,
    const float* __restrict__ pe, unsigned short* __restrict__ x)
{
    const int r = blockIdx.x;
    const int c = threadIdx.x * 4;
    const int id = ids[r];
    const int s = r & (S_ - 1);
    float4 e = *(const float4*)(emb + (size_t)id * D_ + c);
    float4 p = *(const float4*)(pe + (size_t)s * D_ + c);
    ushort4 o;
    o.x = f2bf(e.x + p.x); o.y = f2bf(e.y + p.y);
    o.z = f2bf(e.z + p.z); o.w = f2bf(e.w + p.w);
    *(ushort4*)(x + (size_t)r * D_ + c) = o;
}

// ---------------------------------------------------------------------------
// bf16 MFMA GEMM: double-buffered LDS, raw s_barrier + per-wave vmcnt.
// BM in {64,128}, BN in {64,128}, BK=64. Split-K via gridDim.z (fp32 partials).
// 4 waves in 2x2 layout. Kfull = klen * gridDim.z.
// ---------------------------------------------------------------------------
template<int BM, int BN>
__global__ __launch_bounds__(256) void gemm2(
    const unsigned short* __restrict__ A, const unsigned short* __restrict__ Bt,
    const float* __restrict__ bias, unsigned short* __restrict__ Cb,
    float* __restrict__ Cpart, int N, int klen, int act)
{
    constexpr int NSUB_A = BM / 8;
    constexpr int NSUB_B = BN / 8;
    constexpr int NSUB = NSUB_A + NSUB_B;
    constexpr int NL = NSUB / 4;            // loads per wave per buffer
    constexpr int BUFSZ = NSUB * 1024;
    constexpr int AOFF = NSUB_A * 1024;
    constexpr int WM = BM / 32, WN = BN / 32;
    __shared__ __attribute__((aligned(16))) char smem[2 * BUFSZ];

    const int tid = threadIdx.x;
    const int wave = tid >> 6, lane = tid & 63;
    const int lm = lane & 15, quad = lane >> 4;
    const int wm = wave >> 1, wn = wave & 1;
    const int m0 = blockIdx.y * BM;
    const int n0 = blockIdx.x * BN;
    const int Kfull = klen * gridDim.z;
    const int kb = blockIdx.z * klen;

    floatx4 acc[WM][WN];
#pragma unroll
    for (int i = 0; i < WM; i++)
#pragma unroll
        for (int j = 0; j < WN; j++) acc[i][j] = (floatx4){0.f, 0.f, 0.f, 0.f};

    const unsigned short* ga[NL];
    int loff[NL];
#pragma unroll
    for (int j = 0; j < NL; j++) {
        int sid = wave * NL + j;
        if (sid < NSUB_A) {
            int mi = sid >> 1, ki = sid & 1;
            ga[j] = A + (size_t)(m0 + mi * 16 + lm) * Kfull + kb + ki * 32 + quad * 8;
            loff[j] = sid * 1024;
        } else {
            int t = sid - NSUB_A;
            int ni = t >> 1, ki = t & 1;
            ga[j] = Bt + (size_t)(n0 + ni * 16 + lm) * Kfull + kb + ki * 32 + quad * 8;
            loff[j] = AOFF + t * 1024;
        }
    }

    // prologue: fill buffer 0
#pragma unroll
    for (int j = 0; j < NL; j++) gload_lds16(ga[j], smem + loff[j]);

    for (int kt = 0; kt < klen; kt += 64) {
        char* sc = smem + ((kt >> 6) & 1) * BUFSZ;
        if (kt + 64 < klen) {
            char* sn = smem + (((kt >> 6) + 1) & 1) * BUFSZ;
#pragma unroll
            for (int j = 0; j < NL; j++) gload_lds16(ga[j] + kt + 64, sn + loff[j]);
            __builtin_amdgcn_s_waitcnt(0x0F70 | NL);   // own current-buffer loads done
        } else {
            __builtin_amdgcn_s_waitcnt(0x0F70);        // drain
        }
        asm volatile("" ::: "memory");
        __builtin_amdgcn_s_barrier();
        asm volatile("" ::: "memory");

#pragma unroll
        for (int ki = 0; ki < 2; ki++) {
            bf16x8 af[WM], bfr[WN];
#pragma unroll
            for (int i = 0; i < WM; i++)
                af[i] = *(const bf16x8*)(sc + ((((wm * WM + i) * 2 + ki) << 10) + (lane << 4)));
#pragma unroll
            for (int j = 0; j < WN; j++)
                bfr[j] = *(const bf16x8*)(sc + AOFF + ((((wn * WN + j) * 2 + ki) << 10) + (lane << 4)));
#pragma unroll
            for (int i = 0; i < WM; i++)
#pragma unroll
                for (int j = 0; j < WN; j++)
                    acc[i][j] = __builtin_amdgcn_mfma_f32_16x16x32_bf16(
                        af[i], bfr[j], acc[i][j], 0, 0, 0);
        }
        asm volatile("" ::: "memory");
        __builtin_amdgcn_s_barrier();   // all waves done reading sc before refill
        asm volatile("" ::: "memory");
    }

    if (gridDim.z == 1) {
#pragma unroll
        for (int mi = 0; mi < WM; mi++) {
            const int rb = m0 + wm * (WM * 16) + mi * 16 + quad * 4;
#pragma unroll
            for (int nj = 0; nj < WN; nj++) {
                const int col = n0 + wn * (WN * 16) + nj * 16 + lm;
                const float bv = bias[col];
#pragma unroll
                for (int r = 0; r < 4; r++) {
                    float o = acc[mi][nj][r] + bv;
                    if (act) o = fmaxf(o, 0.f);
                    Cb[(size_t)(rb + r) * N + col] = f2bf(o);
                }
            }
        }
    } else {
        float* Cp = Cpart + (size_t)blockIdx.z * gridDim.y * BM * N;
#pragma unroll
        for (int mi = 0; mi < WM; mi++) {
            const int rb = m0 + wm * (WM * 16) + mi * 16 + quad * 4;
#pragma unroll
            for (int nj = 0; nj < WN; nj++) {
                const int col = n0 + wn * (WN * 16) + nj * 16 + lm;
#pragma unroll
                for (int r = 0; r < 4; r++)
                    Cp[(size_t)(rb + r) * N + col] = acc[mi][nj][r];
            }
        }
    }
}

// ---------------------------------------------------------------------------
// Transpose V slice of qkv into vt[(b*8+h)*64 + d][s]  (bf16)
// ---------------------------------------------------------------------------
__global__ __launch_bounds__(256) void transpose_v(
    const unsigned short* __restrict__ qkv, unsigned short* __restrict__ vt)
{
    __shared__ unsigned short tile[64][74];
    const int tid = threadIdx.x;
    const int bh = blockIdx.y;
    const int b = bh >> 3, h = bh & 7;
    const int s0 = blockIdx.x * 64;
    const int ty = tid >> 3, tx = tid & 7;
#pragma unroll
    for (int i = 0; i < 64; i += 32) {
        uint4 v = *(const uint4*)(qkv + (size_t)(b * 256 + s0 + ty + i) * 1536
                                  + 1024 + h * 64 + tx * 8);
        unsigned short* dstp = &tile[ty + i][tx * 8];
        const unsigned short* sp = (const unsigned short*)&v;
#pragma unroll
        for (int j = 0; j < 8; j++) dstp[j] = sp[j];
    }
    __syncthreads();
#pragma unroll
    for (int i = 0; i < 64; i += 32) {
        int d = ty + i;
        unsigned short tmp[8];
#pragma unroll
        for (int j = 0; j < 8; j++) tmp[j] = tile[tx * 8 + j][d];
        *(uint4*)(vt + (size_t)(bh * 64 + d) * 256 + s0 + tx * 8) = *(uint4*)tmp;
    }
}

// ---------------------------------------------------------------------------
// Fused attention, 64-row Q tiles: grid (4, 128).  S=QK^T (MFMA) ->
// in-register softmax -> P via LDS -> O=PV (MFMA, V from vt) -> /l -> bf16.
// Each wave owns 16 q rows.
// ---------------------------------------------------------------------------
__global__ __launch_bounds__(256) void attn_fused(
    const unsigned short* __restrict__ qkv, const unsigned short* __restrict__ vt,
    const int* __restrict__ lens, unsigned short* __restrict__ o)
{
    __shared__ __attribute__((aligned(16))) char smem[32768];
    const int tid = threadIdx.x;
    const int wave = tid >> 6, lane = tid & 63;
    const int lm = lane & 15, quad = lane >> 4;
    const int qt = blockIdx.x;
    const int bh = blockIdx.y;
    const int b = bh >> 3, h = bh & 7;
    const int len = lens[b];
    const unsigned short* Qb = qkv + ((size_t)b * 256 + qt * 64) * 1536 + h * 64;
    const unsigned short* Kb = qkv + (size_t)b * 256 * 1536 + 512 + h * 64;
    const unsigned short* Vt = vt + (size_t)bh * 64 * 256;
    const int rbase = wave * 16;

    // stage K fragments (32 subtiles of 16 keys x 32 d), 8 per wave
#pragma unroll
    for (int j = 0; j < 8; j++) {
        int sid = wave * 8 + j;
        int nf = sid >> 1, kf = sid & 1;
        gload_lds16(Kb + (size_t)(nf * 16 + lm) * 1536 + kf * 32 + quad * 8,
                    smem + sid * 1024);
    }
    // Q fragments (this wave's 16 rows)
    bf16x8 aq[2];
#pragma unroll
    for (int kf = 0; kf < 2; kf++)
        aq[kf] = *(const bf16x8*)(Qb + (size_t)(rbase + lm) * 1536 + kf * 32 + quad * 8);
    __syncthreads();

    floatx4 accS[16];
#pragma unroll
    for (int nf = 0; nf < 16; nf++) accS[nf] = (floatx4){0.f, 0.f, 0.f, 0.f};

#pragma unroll
    for (int nf = 0; nf < 16; nf++) {
        bf16x8 bk0 = *(const bf16x8*)(smem + (nf * 2 + 0) * 1024 + lane * 16);
        bf16x8 bk1 = *(const bf16x8*)(smem + (nf * 2 + 1) * 1024 + lane * 16);
        accS[nf] = __builtin_amdgcn_mfma_f32_16x16x32_bf16(aq[0], bk0, accS[nf], 0, 0, 0);
        accS[nf] = __builtin_amdgcn_mfma_f32_16x16x32_bf16(aq[1], bk1, accS[nf], 0, 0, 0);
    }

    // mask + scale + softmax (row = rbase + quad*4 + r; row spans the 16-lane group)
    float lrow[4];
    const float scale = 0.125f;
#pragma unroll
    for (int r = 0; r < 4; r++) {
        float mx = -1e30f;
#pragma unroll
        for (int nf = 0; nf < 16; nf++) {
            float s = accS[nf][r] * scale + ((nf * 16 + lm >= len) ? -1e9f : 0.f);
            accS[nf][r] = s;
            mx = fmaxf(mx, s);
        }
#pragma unroll
        for (int off = 1; off < 16; off <<= 1) mx = fmaxf(mx, __shfl_xor(mx, off, 64));
        float sum = 0.f;
#pragma unroll
        for (int nf = 0; nf < 16; nf++) {
            float e = __expf(accS[nf][r] - mx);
            accS[nf][r] = e;
            sum += e;
        }
#pragma unroll
        for (int off = 1; off < 16; off <<= 1) sum += __shfl_xor(sum, off, 64);
        lrow[r] = sum;
    }

    // PV in two key-halves: P half -> LDS (A layout), V frags from vt (global)
    floatx4 accO[4];
#pragma unroll
    for (int nj = 0; nj < 4; nj++) accO[nj] = (floatx4){0.f, 0.f, 0.f, 0.f};

    unsigned short* sP = (unsigned short*)smem;
#pragma unroll
    for (int half = 0; half < 2; half++) {
        __syncthreads();
#pragma unroll
        for (int nf2 = 0; nf2 < 8; nf2++) {
            int nf = half * 8 + nf2;
            int row = rbase + quad * 4;
            int col = nf2 * 16 + lm;
#pragma unroll
            for (int r = 0; r < 4; r++)
                sP[(row + r) * 136 + col] = f2bf(accS[nf][r]);
        }
        __syncthreads();
#pragma unroll
        for (int ks2 = 0; ks2 < 4; ks2++) {
            bf16x8 ap = *(const bf16x8*)(sP + (rbase + lm) * 136 + ks2 * 32 + quad * 8);
            int ks = half * 4 + ks2;
#pragma unroll
            for (int nj = 0; nj < 4; nj++) {
                bf16x8 bv = *(const bf16x8*)(Vt + (size_t)(nj * 16 + lm) * 256
                                             + ks * 32 + quad * 8);
                accO[nj] = __builtin_amdgcn_mfma_f32_16x16x32_bf16(ap, bv, accO[nj], 0, 0, 0);
            }
        }
    }

    // epilogue: normalize by 1/l, write bf16
    float inv[4];
#pragma unroll
    for (int r = 0; r < 4; r++) inv[r] = 1.f / lrow[r];
    const int grow = b * 256 + qt * 64 + rbase + quad * 4;
#pragma unroll
    for (int nj = 0; nj < 4; nj++) {
        const int gcol = h * 64 + nj * 16 + lm;
#pragma unroll
        for (int r = 0; r < 4; r++)
            o[(size_t)(grow + r) * 512 + gcol] = f2bf(accO[nj][r] * inv[r]);
    }
}

// ---------------------------------------------------------------------------
// x = LayerNorm(x + y_bf16) (y already has bias)
// ---------------------------------------------------------------------------
__global__ __launch_bounds__(128) void add_ln_bf16(
    unsigned short* __restrict__ x, const unsigned short* __restrict__ y,
    const float* __restrict__ s, const float* __restrict__ bb)
{
    __shared__ float red[2];
    const int row = blockIdx.x;
    const int tid = threadIdx.x;
    const int c = tid * 4;
    ushort4 xv = *(const ushort4*)(x + (size_t)row * D_ + c);
    ushort4 yv = *(const ushort4*)(y + (size_t)row * D_ + c);
    float h[4];
    h[0] = bf2f(xv.x) + bf2f(yv.x);
    h[1] = bf2f(xv.y) + bf2f(yv.y);
    h[2] = bf2f(xv.z) + bf2f(yv.z);
    h[3] = bf2f(xv.w) + bf2f(yv.w);

    float sum = h[0] + h[1] + h[2] + h[3];
#pragma unroll
    for (int off = 32; off >= 1; off >>= 1) sum += __shfl_xor(sum, off, 64);
    if ((tid & 63) == 0) red[tid >> 6] = sum;
    __syncthreads();
    float mean = (red[0] + red[1]) * (1.f / 512.f);
    __syncthreads();

    float d[4];
    d[0] = h[0] - mean; d[1] = h[1] - mean; d[2] = h[2] - mean; d[3] = h[3] - mean;
    float sq = d[0] * d[0] + d[1] * d[1] + d[2] * d[2] + d[3] * d[3];
#pragma unroll
    for (int off = 32; off >= 1; off >>= 1) sq += __shfl_xor(sq, off, 64);
    if ((tid & 63) == 0) red[tid >> 6] = sq;
    __syncthreads();
    float var = (red[0] + red[1]) * (1.f / 512.f);
    float rs = rsqrtf(var + 1e-5f);

    float4 sv = *(const float4*)(s + c);
    float4 bv = *(const float4*)(bb + c);
    ushort4 ov;
    ov.x = f2bf(d[0] * rs * sv.x + bv.x);
    ov.y = f2bf(d[1] * rs * sv.y + bv.y);
    ov.z = f2bf(d[2] * rs * sv.z + bv.z);
    ov.w = f2bf(d[3] * rs * sv.w + bv.w);
    *(ushort4*)(x + (size_t)row * D_ + c) = ov;
}

// ---------------------------------------------------------------------------
// x = LayerNorm(x + p0 + p1 + bias) (split-K partials, fp32); optional enc out
// ---------------------------------------------------------------------------
__global__ __launch_bounds__(128) void add_ln_part(
    unsigned short* __restrict__ x, const float* __restrict__ p0,
    const float* __restrict__ p1, const float* __restrict__ bias,
    const float* __restrict__ s, const float* __restrict__ bb,
    float* __restrict__ enc_opt)
{
    __shared__ float red[2];
    const int row = blockIdx.x;
    const int tid = threadIdx.x;
    const int c = tid * 4;
    ushort4 xv = *(const ushort4*)(x + (size_t)row * D_ + c);
    float4 a = *(const float4*)(p0 + (size_t)row * D_ + c);
    float4 bq = *(const float4*)(p1 + (size_t)row * D_ + c);
    float4 bi = *(const float4*)(bias + c);
    float h[4];
    h[0] = bf2f(xv.x) + a.x + bq.x + bi.x;
    h[1] = bf2f(xv.y) + a.y + bq.y + bi.y;
    h[2] = bf2f(xv.z) + a.z + bq.z + bi.z;
    h[3] = bf2f(xv.w) + a.w + bq.w + bi.w;

    float sum = h[0] + h[1] + h[2] + h[3];
#pragma unroll
    for (int off = 32; off >= 1; off >>= 1) sum += __shfl_xor(sum, off, 64);
    if ((tid & 63) == 0) red[tid >> 6] = sum;
    __syncthreads();
    float mean = (red[0] + red[1]) * (1.f / 512.f);
    __syncthreads();

    float d[4];
    d[0] = h[0] - mean; d[1] = h[1] - mean; d[2] = h[2] - mean; d[3] = h[3] - mean;
    float sq = d[0] * d[0] + d[1] * d[1] + d[2] * d[2] + d[3] * d[3];
#pragma unroll
    for (int off = 32; off >= 1; off >>= 1) sq += __shfl_xor(sq, off, 64);
    if ((tid & 63) == 0) red[tid >> 6] = sq;
    __syncthreads();
    float var = (red[0] + red[1]) * (1.f / 512.f);
    float rs = rsqrtf(var + 1e-5f);

    float4 sv = *(const float4*)(s + c);
    float4 bv = *(const float4*)(bb + c);
    float o[4];
    o[0] = d[0] * rs * sv.x + bv.x;
    o[1] = d[1] * rs * sv.y + bv.y;
    o[2] = d[2] * rs * sv.z + bv.z;
    o[3] = d[3] * rs * sv.w + bv.w;
    ushort4 ov;
    ov.x = f2bf(o[0]); ov.y = f2bf(o[1]); ov.z = f2bf(o[2]); ov.w = f2bf(o[3]);
    *(ushort4*)(x + (size_t)row * D_ + c) = ov;
    if (enc_opt) {
        float4 e; e.x = o[0]; e.y = o[1]; e.z = o[2]; e.w = o[3];
        *(float4*)(enc_opt + (size_t)row * D_ + c) = e;
    }
}

// ---------------------------------------------------------------------------
// Duration head stage 2 from split-K partials
// ---------------------------------------------------------------------------
__global__ __launch_bounds__(256) void dur_head2(
    const float* __restrict__ p0, const float* __restrict__ p1,
    const float* __restrict__ b1, const float* __restrict__ w2,
    const float* __restrict__ b2, float* __restrict__ durout)
{
    const int tid = threadIdx.x;
    const int w = tid >> 6, lane = tid & 63;
    const int r = blockIdx.x * 4 + w;
    float4 a = *(const float4*)(p0 + (size_t)r * 256 + lane * 4);
    float4 bq = *(const float4*)(p1 + (size_t)r * 256 + lane * 4);
    float4 bi = *(const float4*)(b1 + lane * 4);
    float4 wv = *(const float4*)(w2 + lane * 4);
    float h0 = fmaxf(a.x + bq.x + bi.x, 0.f);
    float h1 = fmaxf(a.y + bq.y + bi.y, 0.f);
    float h2 = fmaxf(a.z + bq.z + bi.z, 0.f);
    float h3 = fmaxf(a.w + bq.w + bi.w, 0.f);
    float p = h0 * wv.x + h1 * wv.y + h2 * wv.z + h3 * wv.w;
#pragma unroll
    for (int off = 32; off >= 1; off >>= 1) p += __shfl_xor(p, off, 64);
    if (lane == 0) {
        float v = p + b2[0];
        durout[r] = (v > 20.f) ? v : log1pf(expf(v));
    }
}

__global__ __launch_bounds__(256) void dur_cumsum(
    const float* __restrict__ dur, int* __restrict__ cum)
{
    __shared__ int sc[256];
    const int b = blockIdx.x, s = threadIdx.x;
    int d = (int)rintf(dur[b * 256 + s]);
    if (d < 1) d = 1;
    sc[s] = d;
    __syncthreads();
    for (int off = 1; off < 256; off <<= 1) {
        int v = sc[s];
        int add = (s >= off) ? sc[s - off] : 0;
        __syncthreads();
        sc[s] = v + add;
        __syncthreads();
    }
    cum[b * 256 + s] = sc[s];
}

__global__ __launch_bounds__(256) void mel_c0(
    const float* __restrict__ b1, const float* __restrict__ W2,
    const float* __restrict__ b2, float* __restrict__ c0)
{
    __shared__ float red[4];
    const int c = blockIdx.x;
    const int tid = threadIdx.x;
    float p = 0.f;
    for (int f = tid; f < 2048; f += 256)
        p += fmaxf(b1[f], 0.f) * W2[(size_t)f * 80 + c];
#pragma unroll
    for (int off = 32; off >= 1; off >>= 1) p += __shfl_xor(p, off, 64);
    if ((tid & 63) == 0) red[tid >> 6] = p;
    __syncthreads();
    if (tid == 0) c0[c] = red[0] + red[1] + red[2] + red[3] + b2[c];
}

// ---------------------------------------------------------------------------
// mel gather v2: LDS-staged rows (coalesced), coalesced writes.
// grid (T/256, 2 col-halves, B). mp = [4][4096][128] fp32 partials.
// ---------------------------------------------------------------------------
__global__ __launch_bounds__(256) void mel_gather2(
    const float* __restrict__ mp, const float* __restrict__ b2,
    const float* __restrict__ c0, const int* __restrict__ cum,
    float* __restrict__ mel_out)
{
    __shared__ float rows[256 * 40];
    __shared__ int sc[256];
    __shared__ float s0[40];
    const int tid = threadIdx.x;
    const int b = blockIdx.z;
    const int cc0 = blockIdx.y * 40;
    sc[tid] = cum[b * 256 + tid];
    if (tid < 40) s0[tid] = c0[cc0 + tid];
    const size_t plane = (size_t)M_ * 128;
    for (int idx = tid; idx < 256 * 40; idx += 256) {
        int r = idx / 40, c = idx - r * 40;
        size_t base = ((size_t)b * 256 + r) * 128 + cc0 + c;
        rows[idx] = mp[base] + mp[plane + base] + mp[2 * plane + base]
                  + mp[3 * plane + base] + b2[cc0 + c];
    }
    __syncthreads();
    const int total = sc[255];
    const int t = blockIdx.x * 256 + tid;
    int lo = 0, hi = 256;
    while (lo < hi) {
        int mid = (lo + hi) >> 1;
        if (sc[mid] <= t) lo = mid + 1; else hi = mid;
    }
    int row = lo < 255 ? lo : 255;
    const bool valid = t < total;
    const float* src = valid ? &rows[row * 40] : s0;
    for (int cc = 0; cc < 40; cc++)
        mel_out[((size_t)b * 80 + cc0 + cc) * T_ + t] = src[cc];
}

// ---------------------------------------------------------------------------
extern "C" void kernel_launch(void* const* d_in, const int* in_sizes, int n_in,
                              void* d_out, int out_size, void* d_ws, size_t ws_size,
                              hipStream_t stream)
{
    const int*   text_ids     = (const int*)d_in[0];
    const int*   text_lengths = (const int*)d_in[1];
    const float* emb   = (const float*)d_in[3];
    const float* pe    = (const float*)d_in[4];
    const float* Wqkv  = (const float*)d_in[5];
    const float* bqkv  = (const float*)d_in[6];
    const float* Wo    = (const float*)d_in[7];
    const float* bo    = (const float*)d_in[8];
    const float* ln1_s = (const float*)d_in[9];
    const float* ln1_b = (const float*)d_in[10];
    const float* ln2_s = (const float*)d_in[11];
    const float* ln2_b = (const float*)d_in[12];
    const float* W1    = (const float*)d_in[13];
    const float* b1    = (const float*)d_in[14];
    const float* W2    = (const float*)d_in[15];
    const float* b2    = (const float*)d_in[16];
    const float* mel_W1 = (const float*)d_in[17];
    const float* mel_b1 = (const float*)d_in[18];
    const float* mel_W2 = (const float*)d_in[19];
    const float* mel_b2 = (const float*)d_in[20];
    const float* dur_W1 = (const float*)d_in[21];
    const float* dur_b1 = (const float*)d_in[22];
    const float* dur_W2 = (const float*)d_in[23];
    const float* dur_b2 = (const float*)d_in[24];

    float* out = (float*)d_out;
    float* mel_out = out;
    float* dur_out = out + (size_t)B_ * NM_ * T_;
    float* enc_out = dur_out + (size_t)B_ * S_;

    typedef unsigned short u16;
    char* w = (char*)d_ws;
    u16* Wqkv_t  = (u16*)w;                   w += (size_t)L_ * 1536 * 512 * 2;
    u16* Wo_t    = (u16*)w;                   w += (size_t)L_ * 512 * 512 * 2;
    u16* W1_t    = (u16*)w;                   w += (size_t)L_ * 2048 * 512 * 2;
    u16* W2_t    = (u16*)w;                   w += (size_t)L_ * 512 * 2048 * 2;
    u16* melW1_t = (u16*)w;                   w += (size_t)2048 * 512 * 2;
    u16* melW2_t = (u16*)w;                   w += (size_t)128 * 2048 * 2;
    u16* durW1_t = (u16*)w;                   w += (size_t)256 * 512 * 2;
    u16* x_bf    = (u16*)w;                   w += (size_t)M_ * 512 * 2;
    u16* qkv_bf  = (u16*)w;                   w += (size_t)M_ * 1536 * 2;  // contiguous with
    u16* ao_bf   = (u16*)w;                   w += (size_t)M_ * 512 * 2;   // ao: 16.78MB union
    u16* y_bf    = (u16*)w;                   w += (size_t)M_ * 512 * 2;
    char* big    = w;                         w += (size_t)16777216;       // ffh/melh (+vt tail)
    float* c0    = (float*)w;                 w += 512;
    int*   cum   = (int*)w;                   w += (size_t)M_ * 4;

    u16* ffh     = (u16*)big;
    u16* melh    = (u16*)big;
    u16* vt      = (u16*)(big + 12582912);    // 4MB tail; disjoint from ffh lifetime

    float* part2 = (float*)qkv_bf;            // [2][4096][512] for FF2
    float* dpart = (float*)qkv_bf;            // [2][4096][256] for dur1
    float* mpart = (float*)(qkv_bf + (size_t)M_ * 512);  // [4][4096][128] for mel2

    // weight conversion
    transpose_bf16<<<dim3(48, 16, 6), dim3(32, 8), 0, stream>>>(Wqkv, Wqkv_t, 512, 1536);
    transpose_bf16<<<dim3(16, 16, 6), dim3(32, 8), 0, stream>>>(Wo, Wo_t, 512, 512);
    transpose_bf16<<<dim3(64, 16, 6), dim3(32, 8), 0, stream>>>(W1, W1_t, 512, 2048);
    transpose_bf16<<<dim3(16, 64, 6), dim3(32, 8), 0, stream>>>(W2, W2_t, 2048, 512);
    transpose_bf16<<<dim3(64, 16, 1), dim3(32, 8), 0, stream>>>(mel_W1, melW1_t, 512, 2048);
    transpose_pad_bf16<<<dim3(4, 64), dim3(32, 8), 0, stream>>>(mel_W2, melW2_t, 2048, 80);
    transpose_bf16<<<dim3(8, 16, 1), dim3(32, 8), 0, stream>>>(dur_W1, durW1_t, 512, 256);

    embed_bf16<<<M_, 128, 0, stream>>>(text_ids, emb, pe, x_bf);

    for (int l = 0; l < L_; l++) {
        gemm2<64, 128><<<dim3(12, 64), 256, 0, stream>>>(
            x_bf, Wqkv_t + (size_t)l * 1536 * 512, bqkv + (size_t)l * 1536,
            qkv_bf, nullptr, 1536, 512, 0);
        transpose_v<<<dim3(4, 128), 256, 0, stream>>>(qkv_bf, vt);
        attn_fused<<<dim3(4, 128), 256, 0, stream>>>(qkv_bf, vt, text_lengths, ao_bf);
        gemm2<64, 64><<<dim3(8, 64), 256, 0, stream>>>(
            ao_bf, Wo_t + (size_t)l * 512 * 512, bo + (size_t)l * 512,
            y_bf, nullptr, 512, 512, 0);
        add_ln_bf16<<<M_, 128, 0, stream>>>(
            x_bf, y_bf, ln1_s + (size_t)l * D_, ln1_b + (size_t)l * D_);
        gemm2<64, 128><<<dim3(16, 64), 256, 0, stream>>>(
            x_bf, W1_t + (size_t)l * 2048 * 512, b1 + (size_t)l * 2048,
            ffh, nullptr, 2048, 512, 1);
        gemm2<64, 64><<<dim3(8, 64, 2), 256, 0, stream>>>(
            ffh, W2_t + (size_t)l * 512 * 2048, nullptr,
            nullptr, part2, 512, 1024, 0);
        add_ln_part<<<M_, 128, 0, stream>>>(
            x_bf, part2, part2 + (size_t)M_ * 512, b2 + (size_t)l * 512,
            ln2_s + (size_t)l * D_, ln2_b + (size_t)l * D_,
            (l == L_ - 1) ? enc_out : nullptr);
    }

    // duration head (split-K=2 partials -> dur_head2 combines)
    gemm2<64, 64><<<dim3(4, 64, 2), 256, 0, stream>>>(
        x_bf, durW1_t, nullptr, nullptr, dpart, 256, 256, 0);
    dur_head2<<<M_ / 4, 256, 0, stream>>>(
        dpart, dpart + (size_t)M_ * 256, dur_b1, dur_W2, dur_b2, dur_out);
    dur_cumsum<<<B_, 256, 0, stream>>>(dur_out, cum);

    // mel head: mel1 (bf16, relu), mel2 (split-K=4 partials -> gather combines)
    gemm2<64, 128><<<dim3(16, 64), 256, 0, stream>>>(
        x_bf, melW1_t, mel_b1, melh, nullptr, 2048, 512, 1);
    gemm2<64, 128><<<dim3(1, 64, 4), 256, 0, stream>>>(
        melh, melW2_t, nullptr, nullptr, mpart, 128, 512, 0);
    mel_c0<<<NM_, 256, 0, stream>>>(mel_b1, mel_W2, mel_b2, c0);
    mel_gather2<<<dim3(T_ / 256, 2, B_), 256, 0, stream>>>(mpart, mel_b2, c0, cum, mel_out);
}

// Round 6
// 862.008 us; speedup vs baseline: 1.1528x; 1.1528x over previous
//
#include <hip/hip_runtime.h>
#include <math.h>

#define B_ 16
#define S_ 256
#define T_ 2048
#define D_ 512
#define H_ 8
#define L_ 6
#define FF_ 2048
#define NM_ 80
#define M_ 4096  // B_*S_

typedef float floatx4 __attribute__((ext_vector_type(4)));
typedef __bf16 bf16x8 __attribute__((ext_vector_type(8)));

__device__ __forceinline__ float bf2f(unsigned u) {
    return __uint_as_float((u & 0xffffu) << 16);
}
__device__ __forceinline__ unsigned short f2bf(float f) {
    unsigned u = __float_as_uint(f);
    unsigned r = u + 0x7fffu + ((u >> 16) & 1u);
    return (unsigned short)(r >> 16);
}
__device__ __forceinline__ void gload_lds16(const void* g, void* l) {
    __builtin_amdgcn_global_load_lds(
        (const __attribute__((address_space(1))) void*)g,
        (__attribute__((address_space(3))) void*)l, 16, 0, 0);
}

// ---------------------------------------------------------------------------
// Tiled transpose + f32->bf16: src [Z][K][N] -> dst [Z][N][K] (bf16)
// ---------------------------------------------------------------------------
__global__ __launch_bounds__(256) void transpose_bf16(
    const float* __restrict__ src, unsigned short* __restrict__ dst,
    int K, int N)
{
    __shared__ float tile[32][33];
    const int k0 = blockIdx.y * 32, n0 = blockIdx.x * 32;
    src += (size_t)blockIdx.z * K * N;
    dst += (size_t)blockIdx.z * K * N;
    const int tx = threadIdx.x, ty = threadIdx.y;
#pragma unroll
    for (int i = 0; i < 32; i += 8)
        tile[ty + i][tx] = src[(size_t)(k0 + ty + i) * N + n0 + tx];
    __syncthreads();
#pragma unroll
    for (int i = 0; i < 32; i += 8)
        dst[(size_t)(n0 + ty + i) * K + k0 + tx] = f2bf(tile[tx][ty + i]);
}

// Transpose with column padding: src [K][Ns] f32 -> dst [Np][K] bf16, rows>=Ns zero
__global__ __launch_bounds__(256) void transpose_pad_bf16(
    const float* __restrict__ src, unsigned short* __restrict__ dst,
    int K, int Ns)
{
    __shared__ float tile[32][33];
    const int k0 = blockIdx.y * 32, n0 = blockIdx.x * 32;
    const int tx = threadIdx.x, ty = threadIdx.y;
#pragma unroll
    for (int i = 0; i < 32; i += 8) {
        int n = n0 + tx;
        tile[ty + i][tx] = (n < Ns) ? src[(size_t)(k0 + ty + i) * Ns + n] : 0.f;
    }
    __syncthreads();
#pragma unroll
    for (int i = 0; i < 32; i += 8)
        dst[(size_t)(n0 + ty + i) * K + k0 + tx] = f2bf(tile[tx][ty + i]);
}

// ---------------------------------------------------------------------------
// Embedding + positional encoding -> bf16 x
// ---------------------------------------------------------------------------
__global__ __launch_bounds__(128) void embed_bf16(
    const int* __restrict__ ids, const float* __restrict__ emb,
    const float* __restrict__ pe, unsigned short* __restrict__ x)
{
    const int r = blockIdx.x;
    const int c = threadIdx.x * 4;
    const int id = ids[r];
    const int s = r & (S_ - 1);
    float4 e = *(const float4*)(emb + (size_t)id * D_ + c);
    float4 p = *(const float4*)(pe + (size_t)s * D_ + c);
    ushort4 o;
    o.x = f2bf(e.x + p.x); o.y = f2bf(e.y + p.y);
    o.z = f2bf(e.z + p.z); o.w = f2bf(e.w + p.w);
    *(ushort4*)(x + (size_t)r * D_ + c) = o;
}

// ---------------------------------------------------------------------------
// bf16 MFMA GEMM: double-buffered LDS, raw s_barrier + per-wave vmcnt.
// BM=128, BN in {128,64}, BK=64. Split-K via gridDim.z (fp32 partials).
// Optional fused V-transpose epilogue (vtp != null, n0 >= 1024, BN=128):
// writes bias-added V columns transposed into vt[(b*8+h)*64+d][s].
// ---------------------------------------------------------------------------
template<int BM, int BN>
__global__ __launch_bounds__(256) void gemm2(
    const unsigned short* __restrict__ A, const unsigned short* __restrict__ Bt,
    const float* __restrict__ bias, unsigned short* __restrict__ Cb,
    float* __restrict__ Cpart, unsigned short* __restrict__ vtp,
    int N, int klen, int act)
{
    constexpr int NSUB_A = BM / 8;
    constexpr int NSUB_B = BN / 8;
    constexpr int NSUB = NSUB_A + NSUB_B;
    constexpr int NL = NSUB / 4;
    constexpr int BUFSZ = NSUB * 1024;
    constexpr int AOFF = NSUB_A * 1024;
    constexpr int WM = BM / 32, WN = BN / 32;
    __shared__ __attribute__((aligned(16))) char smem[2 * BUFSZ];

    const int tid = threadIdx.x;
    const int wave = tid >> 6, lane = tid & 63;
    const int lm = lane & 15, quad = lane >> 4;
    const int wm = wave >> 1, wn = wave & 1;
    const int m0 = blockIdx.y * BM;
    const int n0 = blockIdx.x * BN;
    const int Kfull = klen * gridDim.z;
    const int kb = blockIdx.z * klen;

    floatx4 acc[WM][WN];
#pragma unroll
    for (int i = 0; i < WM; i++)
#pragma unroll
        for (int j = 0; j < WN; j++) acc[i][j] = (floatx4){0.f, 0.f, 0.f, 0.f};

    const unsigned short* ga[NL];
    int loff[NL];
#pragma unroll
    for (int j = 0; j < NL; j++) {
        int sid = wave * NL + j;
        if (sid < NSUB_A) {
            int mi = sid >> 1, ki = sid & 1;
            ga[j] = A + (size_t)(m0 + mi * 16 + lm) * Kfull + kb + ki * 32 + quad * 8;
            loff[j] = sid * 1024;
        } else {
            int t = sid - NSUB_A;
            int ni = t >> 1, ki = t & 1;
            ga[j] = Bt + (size_t)(n0 + ni * 16 + lm) * Kfull + kb + ki * 32 + quad * 8;
            loff[j] = AOFF + t * 1024;
        }
    }

    // prologue: fill buffer 0
#pragma unroll
    for (int j = 0; j < NL; j++) gload_lds16(ga[j], smem + loff[j]);

    for (int kt = 0; kt < klen; kt += 64) {
        char* sc = smem + ((kt >> 6) & 1) * BUFSZ;
        if (kt + 64 < klen) {
            char* sn = smem + (((kt >> 6) + 1) & 1) * BUFSZ;
#pragma unroll
            for (int j = 0; j < NL; j++) gload_lds16(ga[j] + kt + 64, sn + loff[j]);
            __builtin_amdgcn_s_waitcnt(0x0F70 | NL);   // own current-buffer loads done
        } else {
            __builtin_amdgcn_s_waitcnt(0x0F70);        // drain
        }
        asm volatile("" ::: "memory");
        __builtin_amdgcn_s_barrier();
        asm volatile("" ::: "memory");

#pragma unroll
        for (int ki = 0; ki < 2; ki++) {
            bf16x8 af[WM], bfr[WN];
#pragma unroll
            for (int i = 0; i < WM; i++)
                af[i] = *(const bf16x8*)(sc + ((((wm * WM + i) * 2 + ki) << 10) + (lane << 4)));
#pragma unroll
            for (int j = 0; j < WN; j++)
                bfr[j] = *(const bf16x8*)(sc + AOFF + ((((wn * WN + j) * 2 + ki) << 10) + (lane << 4)));
#pragma unroll
            for (int i = 0; i < WM; i++)
#pragma unroll
                for (int j = 0; j < WN; j++)
                    acc[i][j] = __builtin_amdgcn_mfma_f32_16x16x32_bf16(
                        af[i], bfr[j], acc[i][j], 0, 0, 0);
        }
        asm volatile("" ::: "memory");
        __builtin_amdgcn_s_barrier();   // all waves done reading sc before refill
        asm volatile("" ::: "memory");
    }

    if constexpr (BM == 128 && BN == 128) {
        // fused V transpose: write bias-added tile transposed to vt
        if (vtp != nullptr && n0 >= 1024) {
            unsigned short* sT = (unsigned short*)smem;  // [128 d][136 s]
#pragma unroll
            for (int mi = 0; mi < WM; mi++) {
                const int rl = wm * 64 + mi * 16 + quad * 4;   // s-local
#pragma unroll
                for (int nj = 0; nj < WN; nj++) {
                    const int cl = wn * 64 + nj * 16 + lm;     // d-local
                    const float bv = bias[n0 + cl];
                    ushort4 t4;
                    t4.x = f2bf(acc[mi][nj][0] + bv);
                    t4.y = f2bf(acc[mi][nj][1] + bv);
                    t4.z = f2bf(acc[mi][nj][2] + bv);
                    t4.w = f2bf(acc[mi][nj][3] + bv);
                    *(ushort4*)(sT + cl * 136 + rl) = t4;
                }
            }
            __syncthreads();
            const int b = m0 >> 8;
            const int s0 = m0 & 255;
            const int h0 = (n0 - 1024) >> 6;   // 2 heads per block
#pragma unroll
            for (int i = 0; i < 8; i++) {
                int idx = i * 256 + tid;
                int d = idx >> 4, c = idx & 15;
                uint4 v = *(const uint4*)(sT + d * 136 + c * 8);
                int bh = b * 8 + h0 + (d >> 6);
                *(uint4*)(vtp + ((size_t)bh * 64 + (d & 63)) * 256 + s0 + c * 8) = v;
            }
            return;
        }
    }

    if (gridDim.z == 1) {
#pragma unroll
        for (int mi = 0; mi < WM; mi++) {
            const int rb = m0 + wm * (WM * 16) + mi * 16 + quad * 4;
#pragma unroll
            for (int nj = 0; nj < WN; nj++) {
                const int col = n0 + wn * (WN * 16) + nj * 16 + lm;
                const float bv = bias[col];
#pragma unroll
                for (int r = 0; r < 4; r++) {
                    float o = acc[mi][nj][r] + bv;
                    if (act) o = fmaxf(o, 0.f);
                    Cb[(size_t)(rb + r) * N + col] = f2bf(o);
                }
            }
        }
    } else {
        float* Cp = Cpart + (size_t)blockIdx.z * gridDim.y * BM * N;
#pragma unroll
        for (int mi = 0; mi < WM; mi++) {
            const int rb = m0 + wm * (WM * 16) + mi * 16 + quad * 4;
#pragma unroll
            for (int nj = 0; nj < WN; nj++) {
                const int col = n0 + wn * (WN * 16) + nj * 16 + lm;
#pragma unroll
                for (int r = 0; r < 4; r++)
                    Cp[(size_t)(rb + r) * N + col] = acc[mi][nj][r];
            }
        }
    }
}

// ---------------------------------------------------------------------------
// Fused attention (R4-proven): per (q-tile 128, bh). S=QK^T (MFMA) ->
// in-register softmax -> P via LDS (two 128-col halves) -> O=PV -> /l -> bf16.
// ---------------------------------------------------------------------------
__global__ __launch_bounds__(256) void attn_fused(
    const unsigned short* __restrict__ qkv, const unsigned short* __restrict__ vt,
    const int* __restrict__ lens, unsigned short* __restrict__ o)
{
    __shared__ __attribute__((aligned(16))) char smem[34816];
    const int tid = threadIdx.x;
    const int wave = tid >> 6, lane = tid & 63;
    const int lm = lane & 15, quad = lane >> 4;
    const int qt = blockIdx.x;
    const int bh = blockIdx.y;
    const int b = bh >> 3, h = bh & 7;
    const int len = lens[b];
    const unsigned short* Qb = qkv + ((size_t)b * 256 + qt * 128) * 1536 + h * 64;
    const unsigned short* Kb = qkv + (size_t)b * 256 * 1536 + 512 + h * 64;
    const unsigned short* Vt = vt + (size_t)bh * 64 * 256;

#pragma unroll
    for (int j = 0; j < 8; j++) {
        int sid = wave * 8 + j;
        int nf = sid >> 1, kf = sid & 1;
        gload_lds16(Kb + (size_t)(nf * 16 + lm) * 1536 + kf * 32 + quad * 8,
                    smem + sid * 1024);
    }
    bf16x8 aq[2][2];
#pragma unroll
    for (int mi = 0; mi < 2; mi++)
#pragma unroll
        for (int kf = 0; kf < 2; kf++)
            aq[mi][kf] = *(const bf16x8*)(Qb + (size_t)(wave * 32 + mi * 16 + lm) * 1536
                                          + kf * 32 + quad * 8);
    __syncthreads();

    floatx4 accS[2][16];
#pragma unroll
    for (int mi = 0; mi < 2; mi++)
#pragma unroll
        for (int nf = 0; nf < 16; nf++) accS[mi][nf] = (floatx4){0.f, 0.f, 0.f, 0.f};

#pragma unroll
    for (int nf = 0; nf < 16; nf++) {
        bf16x8 bk0 = *(const bf16x8*)(smem + (nf * 2 + 0) * 1024 + lane * 16);
        bf16x8 bk1 = *(const bf16x8*)(smem + (nf * 2 + 1) * 1024 + lane * 16);
        accS[0][nf] = __builtin_amdgcn_mfma_f32_16x16x32_bf16(aq[0][0], bk0, accS[0][nf], 0, 0, 0);
        accS[0][nf] = __builtin_amdgcn_mfma_f32_16x16x32_bf16(aq[0][1], bk1, accS[0][nf], 0, 0, 0);
        accS[1][nf] = __builtin_amdgcn_mfma_f32_16x16x32_bf16(aq[1][0], bk0, accS[1][nf], 0, 0, 0);
        accS[1][nf] = __builtin_amdgcn_mfma_f32_16x16x32_bf16(aq[1][1], bk1, accS[1][nf], 0, 0, 0);
    }

    float lrow[2][4];
    const float scale = 0.125f;
#pragma unroll
    for (int mi = 0; mi < 2; mi++)
#pragma unroll
        for (int r = 0; r < 4; r++) {
            float mx = -1e30f;
#pragma unroll
            for (int nf = 0; nf < 16; nf++) {
                float s = accS[mi][nf][r] * scale + ((nf * 16 + lm >= len) ? -1e9f : 0.f);
                accS[mi][nf][r] = s;
                mx = fmaxf(mx, s);
            }
#pragma unroll
            for (int off = 1; off < 16; off <<= 1) mx = fmaxf(mx, __shfl_xor(mx, off, 64));
            float sum = 0.f;
#pragma unroll
            for (int nf = 0; nf < 16; nf++) {
                float e = __expf(accS[mi][nf][r] - mx);
                accS[mi][nf][r] = e;
                sum += e;
            }
#pragma unroll
            for (int off = 1; off < 16; off <<= 1) sum += __shfl_xor(sum, off, 64);
            lrow[mi][r] = sum;
        }

    floatx4 accO[2][4];
#pragma unroll
    for (int mi = 0; mi < 2; mi++)
#pragma unroll
        for (int nj = 0; nj < 4; nj++) accO[mi][nj] = (floatx4){0.f, 0.f, 0.f, 0.f};

    unsigned short* sP = (unsigned short*)smem;
    const int rbase = wave * 32;
#pragma unroll
    for (int half = 0; half < 2; half++) {
        __syncthreads();
#pragma unroll
        for (int mi = 0; mi < 2; mi++)
#pragma unroll
            for (int nf2 = 0; nf2 < 8; nf2++) {
                int nf = half * 8 + nf2;
                int row = rbase + mi * 16 + quad * 4;
                int col = nf2 * 16 + lm;
#pragma unroll
                for (int r = 0; r < 4; r++)
                    sP[(row + r) * 136 + col] = f2bf(accS[mi][nf][r]);
            }
        __syncthreads();
#pragma unroll
        for (int ks2 = 0; ks2 < 4; ks2++) {
            bf16x8 ap[2];
#pragma unroll
            for (int mi = 0; mi < 2; mi++)
                ap[mi] = *(const bf16x8*)(sP + (rbase + mi * 16 + lm) * 136
                                          + ks2 * 32 + quad * 8);
            int ks = half * 4 + ks2;
#pragma unroll
            for (int nj = 0; nj < 4; nj++) {
                bf16x8 bv = *(const bf16x8*)(Vt + (size_t)(nj * 16 + lm) * 256
                                             + ks * 32 + quad * 8);
                accO[0][nj] = __builtin_amdgcn_mfma_f32_16x16x32_bf16(ap[0], bv, accO[0][nj], 0, 0, 0);
                accO[1][nj] = __builtin_amdgcn_mfma_f32_16x16x32_bf16(ap[1], bv, accO[1][nj], 0, 0, 0);
            }
        }
    }

#pragma unroll
    for (int mi = 0; mi < 2; mi++) {
        float inv[4];
#pragma unroll
        for (int r = 0; r < 4; r++) inv[r] = 1.f / lrow[mi][r];
        const int grow = b * 256 + qt * 128 + rbase + mi * 16 + quad * 4;
#pragma unroll
        for (int nj = 0; nj < 4; nj++) {
            const int gcol = h * 64 + nj * 16 + lm;
#pragma unroll
            for (int r = 0; r < 4; r++)
                o[(size_t)(grow + r) * 512 + gcol] = f2bf(accO[mi][nj][r] * inv[r]);
        }
    }
}

// ---------------------------------------------------------------------------
// x = LayerNorm(x + y_bf16) (y already has bias)
// ---------------------------------------------------------------------------
__global__ __launch_bounds__(128) void add_ln_bf16(
    unsigned short* __restrict__ x, const unsigned short* __restrict__ y,
    const float* __restrict__ s, const float* __restrict__ bb)
{
    __shared__ float red[2];
    const int row = blockIdx.x;
    const int tid = threadIdx.x;
    const int c = tid * 4;
    ushort4 xv = *(const ushort4*)(x + (size_t)row * D_ + c);
    ushort4 yv = *(const ushort4*)(y + (size_t)row * D_ + c);
    float h[4];
    h[0] = bf2f(xv.x) + bf2f(yv.x);
    h[1] = bf2f(xv.y) + bf2f(yv.y);
    h[2] = bf2f(xv.z) + bf2f(yv.z);
    h[3] = bf2f(xv.w) + bf2f(yv.w);

    float sum = h[0] + h[1] + h[2] + h[3];
#pragma unroll
    for (int off = 32; off >= 1; off >>= 1) sum += __shfl_xor(sum, off, 64);
    if ((tid & 63) == 0) red[tid >> 6] = sum;
    __syncthreads();
    float mean = (red[0] + red[1]) * (1.f / 512.f);
    __syncthreads();

    float d[4];
    d[0] = h[0] - mean; d[1] = h[1] - mean; d[2] = h[2] - mean; d[3] = h[3] - mean;
    float sq = d[0] * d[0] + d[1] * d[1] + d[2] * d[2] + d[3] * d[3];
#pragma unroll
    for (int off = 32; off >= 1; off >>= 1) sq += __shfl_xor(sq, off, 64);
    if ((tid & 63) == 0) red[tid >> 6] = sq;
    __syncthreads();
    float var = (red[0] + red[1]) * (1.f / 512.f);
    float rs = rsqrtf(var + 1e-5f);

    float4 sv = *(const float4*)(s + c);
    float4 bv = *(const float4*)(bb + c);
    ushort4 ov;
    ov.x = f2bf(d[0] * rs * sv.x + bv.x);
    ov.y = f2bf(d[1] * rs * sv.y + bv.y);
    ov.z = f2bf(d[2] * rs * sv.z + bv.z);
    ov.w = f2bf(d[3] * rs * sv.w + bv.w);
    *(ushort4*)(x + (size_t)row * D_ + c) = ov;
}

// ---------------------------------------------------------------------------
// x = LayerNorm(x + p0 + p1 + bias) (split-K partials, fp32); optional enc out
// ---------------------------------------------------------------------------
__global__ __launch_bounds__(128) void add_ln_part(
    unsigned short* __restrict__ x, const float* __restrict__ p0,
    const float* __restrict__ p1, const float* __restrict__ bias,
    const float* __restrict__ s, const float* __restrict__ bb,
    float* __restrict__ enc_opt)
{
    __shared__ float red[2];
    const int row = blockIdx.x;
    const int tid = threadIdx.x;
    const int c = tid * 4;
    ushort4 xv = *(const ushort4*)(x + (size_t)row * D_ + c);
    float4 a = *(const float4*)(p0 + (size_t)row * D_ + c);
    float4 bq = *(const float4*)(p1 + (size_t)row * D_ + c);
    float4 bi = *(const float4*)(bias + c);
    float h[4];
    h[0] = bf2f(xv.x) + a.x + bq.x + bi.x;
    h[1] = bf2f(xv.y) + a.y + bq.y + bi.y;
    h[2] = bf2f(xv.z) + a.z + bq.z + bi.z;
    h[3] = bf2f(xv.w) + a.w + bq.w + bi.w;

    float sum = h[0] + h[1] + h[2] + h[3];
#pragma unroll
    for (int off = 32; off >= 1; off >>= 1) sum += __shfl_xor(sum, off, 64);
    if ((tid & 63) == 0) red[tid >> 6] = sum;
    __syncthreads();
    float mean = (red[0] + red[1]) * (1.f / 512.f);
    __syncthreads();

    float d[4];
    d[0] = h[0] - mean; d[1] = h[1] - mean; d[2] = h[2] - mean; d[3] = h[3] - mean;
    float sq = d[0] * d[0] + d[1] * d[1] + d[2] * d[2] + d[3] * d[3];
#pragma unroll
    for (int off = 32; off >= 1; off >>= 1) sq += __shfl_xor(sq, off, 64);
    if ((tid & 63) == 0) red[tid >> 6] = sq;
    __syncthreads();
    float var = (red[0] + red[1]) * (1.f / 512.f);
    float rs = rsqrtf(var + 1e-5f);

    float4 sv = *(const float4*)(s + c);
    float4 bv = *(const float4*)(bb + c);
    float o[4];
    o[0] = d[0] * rs * sv.x + bv.x;
    o[1] = d[1] * rs * sv.y + bv.y;
    o[2] = d[2] * rs * sv.z + bv.z;
    o[3] = d[3] * rs * sv.w + bv.w;
    ushort4 ov;
    ov.x = f2bf(o[0]); ov.y = f2bf(o[1]); ov.z = f2bf(o[2]); ov.w = f2bf(o[3]);
    *(ushort4*)(x + (size_t)row * D_ + c) = ov;
    if (enc_opt) {
        float4 e; e.x = o[0]; e.y = o[1]; e.z = o[2]; e.w = o[3];
        *(float4*)(enc_opt + (size_t)row * D_ + c) = e;
    }
}

// ---------------------------------------------------------------------------
// Duration head stage 2 from split-K partials
// ---------------------------------------------------------------------------
__global__ __launch_bounds__(256) void dur_head2(
    const float* __restrict__ p0, const float* __restrict__ p1,
    const float* __restrict__ b1, const float* __restrict__ w2,
    const float* __restrict__ b2, float* __restrict__ durout)
{
    const int tid = threadIdx.x;
    const int w = tid >> 6, lane = tid & 63;
    const int r = blockIdx.x * 4 + w;
    float4 a = *(const float4*)(p0 + (size_t)r * 256 + lane * 4);
    float4 bq = *(const float4*)(p1 + (size_t)r * 256 + lane * 4);
    float4 bi = *(const float4*)(b1 + lane * 4);
    float4 wv = *(const float4*)(w2 + lane * 4);
    float h0 = fmaxf(a.x + bq.x + bi.x, 0.f);
    float h1 = fmaxf(a.y + bq.y + bi.y, 0.f);
    float h2 = fmaxf(a.z + bq.z + bi.z, 0.f);
    float h3 = fmaxf(a.w + bq.w + bi.w, 0.f);
    float p = h0 * wv.x + h1 * wv.y + h2 * wv.z + h3 * wv.w;
#pragma unroll
    for (int off = 32; off >= 1; off >>= 1) p += __shfl_xor(p, off, 64);
    if (lane == 0) {
        float v = p + b2[0];
        durout[r] = (v > 20.f) ? v : log1pf(expf(v));
    }
}

__global__ __launch_bounds__(256) void dur_cumsum(
    const float* __restrict__ dur, int* __restrict__ cum)
{
    __shared__ int sc[256];
    const int b = blockIdx.x, s = threadIdx.x;
    int d = (int)rintf(dur[b * 256 + s]);
    if (d < 1) d = 1;
    sc[s] = d;
    __syncthreads();
    for (int off = 1; off < 256; off <<= 1) {
        int v = sc[s];
        int add = (s >= off) ? sc[s - off] : 0;
        __syncthreads();
        sc[s] = v + add;
        __syncthreads();
    }
    cum[b * 256 + s] = sc[s];
}

__global__ __launch_bounds__(256) void mel_c0(
    const float* __restrict__ b1, const float* __restrict__ W2,
    const float* __restrict__ b2, float* __restrict__ c0)
{
    __shared__ float red[4];
    const int c = blockIdx.x;
    const int tid = threadIdx.x;
    float p = 0.f;
    for (int f = tid; f < 2048; f += 256)
        p += fmaxf(b1[f], 0.f) * W2[(size_t)f * 80 + c];
#pragma unroll
    for (int off = 32; off >= 1; off >>= 1) p += __shfl_xor(p, off, 64);
    if ((tid & 63) == 0) red[tid >> 6] = p;
    __syncthreads();
    if (tid == 0) c0[c] = red[0] + red[1] + red[2] + red[3] + b2[c];
}

// ---------------------------------------------------------------------------
// mel gather v2: LDS-staged rows (coalesced), coalesced writes.
// grid (T/256, 2 col-halves, B). mp = [4][4096][128] fp32 partials.
// ---------------------------------------------------------------------------
__global__ __launch_bounds__(256) void mel_gather2(
    const float* __restrict__ mp, const float* __restrict__ b2,
    const float* __restrict__ c0, const int* __restrict__ cum,
    float* __restrict__ mel_out)
{
    __shared__ float rows[256 * 40];
    __shared__ int sc[256];
    __shared__ float s0[40];
    const int tid = threadIdx.x;
    const int b = blockIdx.z;
    const int cc0 = blockIdx.y * 40;
    sc[tid] = cum[b * 256 + tid];
    if (tid < 40) s0[tid] = c0[cc0 + tid];
    const size_t plane = (size_t)M_ * 128;
    for (int idx = tid; idx < 256 * 40; idx += 256) {
        int r = idx / 40, c = idx - r * 40;
        size_t base = ((size_t)b * 256 + r) * 128 + cc0 + c;
        rows[idx] = mp[base] + mp[plane + base] + mp[2 * plane + base]
                  + mp[3 * plane + base] + b2[cc0 + c];
    }
    __syncthreads();
    const int total = sc[255];
    const int t = blockIdx.x * 256 + tid;
    int lo = 0, hi = 256;
    while (lo < hi) {
        int mid = (lo + hi) >> 1;
        if (sc[mid] <= t) lo = mid + 1; else hi = mid;
    }
    int row = lo < 255 ? lo : 255;
    const bool valid = t < total;
    const float* src = valid ? &rows[row * 40] : s0;
    for (int cc = 0; cc < 40; cc++)
        mel_out[((size_t)b * 80 + cc0 + cc) * T_ + t] = src[cc];
}

// ---------------------------------------------------------------------------
extern "C" void kernel_launch(void* const* d_in, const int* in_sizes, int n_in,
                              void* d_out, int out_size, void* d_ws, size_t ws_size,
                              hipStream_t stream)
{
    const int*   text_ids     = (const int*)d_in[0];
    const int*   text_lengths = (const int*)d_in[1];
    const float* emb   = (const float*)d_in[3];
    const float* pe    = (const float*)d_in[4];
    const float* Wqkv  = (const float*)d_in[5];
    const float* bqkv  = (const float*)d_in[6];
    const float* Wo    = (const float*)d_in[7];
    const float* bo    = (const float*)d_in[8];
    const float* ln1_s = (const float*)d_in[9];
    const float* ln1_b = (const float*)d_in[10];
    const float* ln2_s = (const float*)d_in[11];
    const float* ln2_b = (const float*)d_in[12];
    const float* W1    = (const float*)d_in[13];
    const float* b1    = (const float*)d_in[14];
    const float* W2    = (const float*)d_in[15];
    const float* b2    = (const float*)d_in[16];
    const float* mel_W1 = (const float*)d_in[17];
    const float* mel_b1 = (const float*)d_in[18];
    const float* mel_W2 = (const float*)d_in[19];
    const float* mel_b2 = (const float*)d_in[20];
    const float* dur_W1 = (const float*)d_in[21];
    const float* dur_b1 = (const float*)d_in[22];
    const float* dur_W2 = (const float*)d_in[23];
    const float* dur_b2 = (const float*)d_in[24];

    float* out = (float*)d_out;
    float* mel_out = out;
    float* dur_out = out + (size_t)B_ * NM_ * T_;
    float* enc_out = dur_out + (size_t)B_ * S_;

    typedef unsigned short u16;
    char* w = (char*)d_ws;
    u16* Wqkv_t  = (u16*)w;                   w += (size_t)L_ * 1536 * 512 * 2;
    u16* Wo_t    = (u16*)w;                   w += (size_t)L_ * 512 * 512 * 2;
    u16* W1_t    = (u16*)w;                   w += (size_t)L_ * 2048 * 512 * 2;
    u16* W2_t    = (u16*)w;                   w += (size_t)L_ * 512 * 2048 * 2;
    u16* melW1_t = (u16*)w;                   w += (size_t)2048 * 512 * 2;
    u16* melW2_t = (u16*)w;                   w += (size_t)128 * 2048 * 2;
    u16* durW1_t = (u16*)w;                   w += (size_t)256 * 512 * 2;
    u16* x_bf    = (u16*)w;                   w += (size_t)M_ * 512 * 2;
    u16* qkv_bf  = (u16*)w;                   w += (size_t)M_ * 1536 * 2;  // contiguous with
    u16* ao_bf   = (u16*)w;                   w += (size_t)M_ * 512 * 2;   // ao: 16.78MB union
    u16* y_bf    = (u16*)w;                   w += (size_t)M_ * 512 * 2;
    char* big    = w;                         w += (size_t)16777216;       // ffh/melh (+vt tail)
    float* c0    = (float*)w;                 w += 512;
    int*   cum   = (int*)w;                   w += (size_t)M_ * 4;

    u16* ffh     = (u16*)big;
    u16* melh    = (u16*)big;
    u16* vt      = (u16*)(big + 12582912);    // 4MB tail; disjoint from ffh lifetime

    float* part2 = (float*)qkv_bf;            // [2][4096][512] for FF2
    float* dpart = (float*)qkv_bf;            // [2][4096][256] for dur1
    float* mpart = (float*)(qkv_bf + (size_t)M_ * 512);  // [4][4096][128] for mel2

    // weight conversion
    transpose_bf16<<<dim3(48, 16, 6), dim3(32, 8), 0, stream>>>(Wqkv, Wqkv_t, 512, 1536);
    transpose_bf16<<<dim3(16, 16, 6), dim3(32, 8), 0, stream>>>(Wo, Wo_t, 512, 512);
    transpose_bf16<<<dim3(64, 16, 6), dim3(32, 8), 0, stream>>>(W1, W1_t, 512, 2048);
    transpose_bf16<<<dim3(16, 64, 6), dim3(32, 8), 0, stream>>>(W2, W2_t, 2048, 512);
    transpose_bf16<<<dim3(64, 16, 1), dim3(32, 8), 0, stream>>>(mel_W1, melW1_t, 512, 2048);
    transpose_pad_bf16<<<dim3(4, 64), dim3(32, 8), 0, stream>>>(mel_W2, melW2_t, 2048, 80);
    transpose_bf16<<<dim3(8, 16, 1), dim3(32, 8), 0, stream>>>(dur_W1, durW1_t, 512, 256);

    embed_bf16<<<M_, 128, 0, stream>>>(text_ids, emb, pe, x_bf);

    for (int l = 0; l < L_; l++) {
        // QKV with fused V-transpose epilogue (V cols -> vt, Q/K cols -> qkv_bf)
        gemm2<128, 128><<<dim3(12, 32), 256, 0, stream>>>(
            x_bf, Wqkv_t + (size_t)l * 1536 * 512, bqkv + (size_t)l * 1536,
            qkv_bf, nullptr, vt, 1536, 512, 0);
        attn_fused<<<dim3(2, 128), 256, 0, stream>>>(qkv_bf, vt, text_lengths, ao_bf);
        gemm2<128, 64><<<dim3(8, 32), 256, 0, stream>>>(
            ao_bf, Wo_t + (size_t)l * 512 * 512, bo + (size_t)l * 512,
            y_bf, nullptr, nullptr, 512, 512, 0);
        add_ln_bf16<<<M_, 128, 0, stream>>>(
            x_bf, y_bf, ln1_s + (size_t)l * D_, ln1_b + (size_t)l * D_);
        gemm2<128, 128><<<dim3(16, 32), 256, 0, stream>>>(
            x_bf, W1_t + (size_t)l * 2048 * 512, b1 + (size_t)l * 2048,
            ffh, nullptr, nullptr, 2048, 512, 1);
        gemm2<128, 64><<<dim3(8, 32, 2), 256, 0, stream>>>(
            ffh, W2_t + (size_t)l * 512 * 2048, nullptr,
            nullptr, part2, nullptr, 512, 1024, 0);
        add_ln_part<<<M_, 128, 0, stream>>>(
            x_bf, part2, part2 + (size_t)M_ * 512, b2 + (size_t)l * 512,
            ln2_s + (size_t)l * D_, ln2_b + (size_t)l * D_,
            (l == L_ - 1) ? enc_out : nullptr);
    }

    // duration head (split-K=2 partials -> dur_head2 combines)
    gemm2<128, 64><<<dim3(4, 32, 2), 256, 0, stream>>>(
        x_bf, durW1_t, nullptr, nullptr, dpart, nullptr, 256, 256, 0);
    dur_head2<<<M_ / 4, 256, 0, stream>>>(
        dpart, dpart + (size_t)M_ * 256, dur_b1, dur_W2, dur_b2, dur_out);
    dur_cumsum<<<B_, 256, 0, stream>>>(dur_out, cum);

    // mel head: mel1 (bf16, relu), mel2 (split-K=4 partials -> gather combines)
    gemm2<128, 128><<<dim3(16, 32), 256, 0, stream>>>(
        x_bf, melW1_t, mel_b1, melh, nullptr, nullptr, 2048, 512, 1);
    gemm2<128, 64><<<dim3(2, 32, 4), 256, 0, stream>>>(
        melh, melW2_t, nullptr, nullptr, mpart, nullptr, 128, 512, 0);
    mel_c0<<<NM_, 256, 0, stream>>>(mel_b1, mel_W2, mel_b2, c0);
    mel_gather2<<<dim3(T_ / 256, 2, B_), 256, 0, stream>>>(mpart, mel_b2, c0, cum, mel_out);
}

// Round 7
// 860.302 us; speedup vs baseline: 1.1551x; 1.0020x over previous
//
#include <hip/hip_runtime.h>
#include <math.h>

#define B_ 16
#define S_ 256
#define T_ 2048
#define D_ 512
#define H_ 8
#define L_ 6
#define FF_ 2048
#define NM_ 80
#define M_ 4096  // B_*S_

typedef float floatx4 __attribute__((ext_vector_type(4)));
typedef __bf16 bf16x8 __attribute__((ext_vector_type(8)));

__device__ __forceinline__ float bf2f(unsigned u) {
    return __uint_as_float((u & 0xffffu) << 16);
}
__device__ __forceinline__ unsigned short f2bf(float f) {
    unsigned u = __float_as_uint(f);
    unsigned r = u + 0x7fffu + ((u >> 16) & 1u);
    return (unsigned short)(r >> 16);
}
__device__ __forceinline__ void gload_lds16(const void* g, void* l) {
    __builtin_amdgcn_global_load_lds(
        (const __attribute__((address_space(1))) void*)g,
        (__attribute__((address_space(3))) void*)l, 16, 0, 0);
}

// ---------------------------------------------------------------------------
// Fused weight prep: all transposes (f32 [K][N] -> bf16 [N][K]) + mel_c0,
// one flat grid, case-switched on block ranges.
// ---------------------------------------------------------------------------
__device__ __forceinline__ void tr_body(
    const float* __restrict__ src, unsigned short* __restrict__ dst,
    int K, int N, int bx, int by, int bz, float (*tile)[33], int Ns /*pad guard*/)
{
    const int k0 = by * 32, n0 = bx * 32;
    src += (size_t)bz * K * Ns;
    dst += (size_t)bz * K * N;
    const int tid = threadIdx.x;
    const int tx = tid & 31, ty = tid >> 5;
#pragma unroll
    for (int i = 0; i < 32; i += 8) {
        int n = n0 + tx;
        tile[ty + i][tx] = (n < Ns) ? src[(size_t)(k0 + ty + i) * Ns + n] : 0.f;
    }
    __syncthreads();
#pragma unroll
    for (int i = 0; i < 32; i += 8)
        dst[(size_t)(n0 + ty + i) * K + k0 + tx] = f2bf(tile[tx][ty + i]);
}

__global__ __launch_bounds__(256) void prep_weights(
    const float* __restrict__ Wqkv, const float* __restrict__ Wo,
    const float* __restrict__ W1, const float* __restrict__ W2,
    const float* __restrict__ melW1, const float* __restrict__ melW2,
    const float* __restrict__ durW1, const float* __restrict__ melb1,
    const float* __restrict__ melb2,
    unsigned short* __restrict__ Wqkv_t, unsigned short* __restrict__ Wo_t,
    unsigned short* __restrict__ W1_t, unsigned short* __restrict__ W2_t,
    unsigned short* __restrict__ melW1_t, unsigned short* __restrict__ melW2_t,
    unsigned short* __restrict__ durW1_t, float* __restrict__ c0)
{
    __shared__ float tile[32][33];
    int bid = blockIdx.x;
    if (bid < 4608) {            // Wqkv: 48 x 16 x 6
        int z = bid / 768, r = bid % 768;
        tr_body(Wqkv, Wqkv_t, 512, 1536, r % 48, r / 48, z, tile, 1536);
        return;
    }
    bid -= 4608;
    if (bid < 1536) {            // Wo: 16 x 16 x 6
        int z = bid / 256, r = bid % 256;
        tr_body(Wo, Wo_t, 512, 512, r % 16, r / 16, z, tile, 512);
        return;
    }
    bid -= 1536;
    if (bid < 6144) {            // W1: 64 x 16 x 6
        int z = bid / 1024, r = bid % 1024;
        tr_body(W1, W1_t, 512, 2048, r % 64, r / 64, z, tile, 2048);
        return;
    }
    bid -= 6144;
    if (bid < 6144) {            // W2: 16 x 64 x 6
        int z = bid / 1024, r = bid % 1024;
        tr_body(W2, W2_t, 2048, 512, r % 16, r / 16, z, tile, 512);
        return;
    }
    bid -= 6144;
    if (bid < 1024) {            // melW1: 64 x 16
        tr_body(melW1, melW1_t, 512, 2048, bid % 64, bid / 64, 0, tile, 2048);
        return;
    }
    bid -= 1024;
    if (bid < 256) {             // melW2 pad: 4 x 64 (dst N=128, src Ns=80)
        tr_body(melW2, melW2_t, 2048, 128, bid % 4, bid / 4, 0, tile, 80);
        return;
    }
    bid -= 256;
    if (bid < 128) {             // durW1: 8 x 16
        tr_body(durW1, durW1_t, 512, 256, bid % 8, bid / 8, 0, tile, 256);
        return;
    }
    bid -= 128;
    {                            // mel_c0: 80 blocks
        float* red = (float*)tile;
        const int c = bid;
        const int tid = threadIdx.x;
        float p = 0.f;
        for (int f = tid; f < 2048; f += 256)
            p += fmaxf(melb1[f], 0.f) * melW2[(size_t)f * 80 + c];
#pragma unroll
        for (int off = 32; off >= 1; off >>= 1) p += __shfl_xor(p, off, 64);
        if ((tid & 63) == 0) red[tid >> 6] = p;
        __syncthreads();
        if (tid == 0) c0[c] = red[0] + red[1] + red[2] + red[3] + melb2[c];
    }
}

// ---------------------------------------------------------------------------
// Embedding + positional encoding -> bf16 x
// ---------------------------------------------------------------------------
__global__ __launch_bounds__(128) void embed_bf16(
    const int* __restrict__ ids, const float* __restrict__ emb,
    const float* __restrict__ pe, unsigned short* __restrict__ x)
{
    const int r = blockIdx.x;
    const int c = threadIdx.x * 4;
    const int id = ids[r];
    const int s = r & (S_ - 1);
    float4 e = *(const float4*)(emb + (size_t)id * D_ + c);
    float4 p = *(const float4*)(pe + (size_t)s * D_ + c);
    ushort4 o;
    o.x = f2bf(e.x + p.x); o.y = f2bf(e.y + p.y);
    o.z = f2bf(e.z + p.z); o.w = f2bf(e.w + p.w);
    *(ushort4*)(x + (size_t)r * D_ + c) = o;
}

// ---------------------------------------------------------------------------
// bf16 MFMA GEMM: double-buffered LDS, raw s_barrier + per-wave vmcnt.
// BM=128, BN in {128,64}, BK=64. Split-K via gridDim.z (fp32 partials).
// Optional fused V-transpose epilogue (vtp != null, n0 >= 1024, BN=128).
// ---------------------------------------------------------------------------
template<int BM, int BN>
__global__ __launch_bounds__(256) void gemm2(
    const unsigned short* __restrict__ A, const unsigned short* __restrict__ Bt,
    const float* __restrict__ bias, unsigned short* __restrict__ Cb,
    float* __restrict__ Cpart, unsigned short* __restrict__ vtp,
    int N, int klen, int act)
{
    constexpr int NSUB_A = BM / 8;
    constexpr int NSUB_B = BN / 8;
    constexpr int NSUB = NSUB_A + NSUB_B;
    constexpr int NL = NSUB / 4;
    constexpr int BUFSZ = NSUB * 1024;
    constexpr int AOFF = NSUB_A * 1024;
    constexpr int WM = BM / 32, WN = BN / 32;
    __shared__ __attribute__((aligned(16))) char smem[2 * BUFSZ];

    const int tid = threadIdx.x;
    const int wave = tid >> 6, lane = tid & 63;
    const int lm = lane & 15, quad = lane >> 4;
    const int wm = wave >> 1, wn = wave & 1;
    const int m0 = blockIdx.y * BM;
    const int n0 = blockIdx.x * BN;
    const int Kfull = klen * gridDim.z;
    const int kb = blockIdx.z * klen;

    floatx4 acc[WM][WN];
#pragma unroll
    for (int i = 0; i < WM; i++)
#pragma unroll
        for (int j = 0; j < WN; j++) acc[i][j] = (floatx4){0.f, 0.f, 0.f, 0.f};

    const unsigned short* ga[NL];
    int loff[NL];
#pragma unroll
    for (int j = 0; j < NL; j++) {
        int sid = wave * NL + j;
        if (sid < NSUB_A) {
            int mi = sid >> 1, ki = sid & 1;
            ga[j] = A + (size_t)(m0 + mi * 16 + lm) * Kfull + kb + ki * 32 + quad * 8;
            loff[j] = sid * 1024;
        } else {
            int t = sid - NSUB_A;
            int ni = t >> 1, ki = t & 1;
            ga[j] = Bt + (size_t)(n0 + ni * 16 + lm) * Kfull + kb + ki * 32 + quad * 8;
            loff[j] = AOFF + t * 1024;
        }
    }

    // prologue: fill buffer 0
#pragma unroll
    for (int j = 0; j < NL; j++) gload_lds16(ga[j], smem + loff[j]);

    for (int kt = 0; kt < klen; kt += 64) {
        char* sc = smem + ((kt >> 6) & 1) * BUFSZ;
        if (kt + 64 < klen) {
            char* sn = smem + (((kt >> 6) + 1) & 1) * BUFSZ;
#pragma unroll
            for (int j = 0; j < NL; j++) gload_lds16(ga[j] + kt + 64, sn + loff[j]);
            __builtin_amdgcn_s_waitcnt(0x0F70 | NL);   // own current-buffer loads done
        } else {
            __builtin_amdgcn_s_waitcnt(0x0F70);        // drain
        }
        asm volatile("" ::: "memory");
        __builtin_amdgcn_s_barrier();
        asm volatile("" ::: "memory");

#pragma unroll
        for (int ki = 0; ki < 2; ki++) {
            bf16x8 af[WM], bfr[WN];
#pragma unroll
            for (int i = 0; i < WM; i++)
                af[i] = *(const bf16x8*)(sc + ((((wm * WM + i) * 2 + ki) << 10) + (lane << 4)));
#pragma unroll
            for (int j = 0; j < WN; j++)
                bfr[j] = *(const bf16x8*)(sc + AOFF + ((((wn * WN + j) * 2 + ki) << 10) + (lane << 4)));
#pragma unroll
            for (int i = 0; i < WM; i++)
#pragma unroll
                for (int j = 0; j < WN; j++)
                    acc[i][j] = __builtin_amdgcn_mfma_f32_16x16x32_bf16(
                        af[i], bfr[j], acc[i][j], 0, 0, 0);
        }
        asm volatile("" ::: "memory");
        __builtin_amdgcn_s_barrier();   // all waves done reading sc before refill
        asm volatile("" ::: "memory");
    }

    if constexpr (BM == 128 && BN == 128) {
        // fused V transpose: write bias-added tile transposed to vt
        if (vtp != nullptr && n0 >= 1024) {
            unsigned short* sT = (unsigned short*)smem;  // [128 d][136 s]
#pragma unroll
            for (int mi = 0; mi < WM; mi++) {
                const int rl = wm * 64 + mi * 16 + quad * 4;   // s-local
#pragma unroll
                for (int nj = 0; nj < WN; nj++) {
                    const int cl = wn * 64 + nj * 16 + lm;     // d-local
                    const float bv = bias[n0 + cl];
                    ushort4 t4;
                    t4.x = f2bf(acc[mi][nj][0] + bv);
                    t4.y = f2bf(acc[mi][nj][1] + bv);
                    t4.z = f2bf(acc[mi][nj][2] + bv);
                    t4.w = f2bf(acc[mi][nj][3] + bv);
                    *(ushort4*)(sT + cl * 136 + rl) = t4;
                }
            }
            __syncthreads();
            const int b = m0 >> 8;
            const int s0 = m0 & 255;
            const int h0 = (n0 - 1024) >> 6;   // 2 heads per block
#pragma unroll
            for (int i = 0; i < 8; i++) {
                int idx = i * 256 + tid;
                int d = idx >> 4, c = idx & 15;
                uint4 v = *(const uint4*)(sT + d * 136 + c * 8);
                int bh = b * 8 + h0 + (d >> 6);
                *(uint4*)(vtp + ((size_t)bh * 64 + (d & 63)) * 256 + s0 + c * 8) = v;
            }
            return;
        }
    }

    if (gridDim.z == 1) {
#pragma unroll
        for (int mi = 0; mi < WM; mi++) {
            const int rb = m0 + wm * (WM * 16) + mi * 16 + quad * 4;
#pragma unroll
            for (int nj = 0; nj < WN; nj++) {
                const int col = n0 + wn * (WN * 16) + nj * 16 + lm;
                const float bv = bias[col];
#pragma unroll
                for (int r = 0; r < 4; r++) {
                    float o = acc[mi][nj][r] + bv;
                    if (act) o = fmaxf(o, 0.f);
                    Cb[(size_t)(rb + r) * N + col] = f2bf(o);
                }
            }
        }
    } else {
        float* Cp = Cpart + (size_t)blockIdx.z * gridDim.y * BM * N;
#pragma unroll
        for (int mi = 0; mi < WM; mi++) {
            const int rb = m0 + wm * (WM * 16) + mi * 16 + quad * 4;
#pragma unroll
            for (int nj = 0; nj < WN; nj++) {
                const int col = n0 + wn * (WN * 16) + nj * 16 + lm;
#pragma unroll
                for (int r = 0; r < 4; r++)
                    Cp[(size_t)(rb + r) * N + col] = acc[mi][nj][r];
            }
        }
    }
}

// ---------------------------------------------------------------------------
// Fused attention: per (q-tile 128, bh). S=QK^T (MFMA) -> in-register softmax
// -> P via LDS (two 128-col halves) -> O=PV -> /l -> bf16.
// ---------------------------------------------------------------------------
__global__ __launch_bounds__(256) void attn_fused(
    const unsigned short* __restrict__ qkv, const unsigned short* __restrict__ vt,
    const int* __restrict__ lens, unsigned short* __restrict__ o)
{
    __shared__ __attribute__((aligned(16))) char smem[34816];
    const int tid = threadIdx.x;
    const int wave = tid >> 6, lane = tid & 63;
    const int lm = lane & 15, quad = lane >> 4;
    const int qt = blockIdx.x;
    const int bh = blockIdx.y;
    const int b = bh >> 3, h = bh & 7;
    const int len = lens[b];
    const unsigned short* Qb = qkv + ((size_t)b * 256 + qt * 128) * 1536 + h * 64;
    const unsigned short* Kb = qkv + (size_t)b * 256 * 1536 + 512 + h * 64;
    const unsigned short* Vt = vt + (size_t)bh * 64 * 256;

#pragma unroll
    for (int j = 0; j < 8; j++) {
        int sid = wave * 8 + j;
        int nf = sid >> 1, kf = sid & 1;
        gload_lds16(Kb + (size_t)(nf * 16 + lm) * 1536 + kf * 32 + quad * 8,
                    smem + sid * 1024);
    }
    bf16x8 aq[2][2];
#pragma unroll
    for (int mi = 0; mi < 2; mi++)
#pragma unroll
        for (int kf = 0; kf < 2; kf++)
            aq[mi][kf] = *(const bf16x8*)(Qb + (size_t)(wave * 32 + mi * 16 + lm) * 1536
                                          + kf * 32 + quad * 8);
    __syncthreads();

    floatx4 accS[2][16];
#pragma unroll
    for (int mi = 0; mi < 2; mi++)
#pragma unroll
        for (int nf = 0; nf < 16; nf++) accS[mi][nf] = (floatx4){0.f, 0.f, 0.f, 0.f};

#pragma unroll
    for (int nf = 0; nf < 16; nf++) {
        bf16x8 bk0 = *(const bf16x8*)(smem + (nf * 2 + 0) * 1024 + lane * 16);
        bf16x8 bk1 = *(const bf16x8*)(smem + (nf * 2 + 1) * 1024 + lane * 16);
        accS[0][nf] = __builtin_amdgcn_mfma_f32_16x16x32_bf16(aq[0][0], bk0, accS[0][nf], 0, 0, 0);
        accS[0][nf] = __builtin_amdgcn_mfma_f32_16x16x32_bf16(aq[0][1], bk1, accS[0][nf], 0, 0, 0);
        accS[1][nf] = __builtin_amdgcn_mfma_f32_16x16x32_bf16(aq[1][0], bk0, accS[1][nf], 0, 0, 0);
        accS[1][nf] = __builtin_amdgcn_mfma_f32_16x16x32_bf16(aq[1][1], bk1, accS[1][nf], 0, 0, 0);
    }

    float lrow[2][4];
    const float scale = 0.125f;
#pragma unroll
    for (int mi = 0; mi < 2; mi++)
#pragma unroll
        for (int r = 0; r < 4; r++) {
            float mx = -1e30f;
#pragma unroll
            for (int nf = 0; nf < 16; nf++) {
                float s = accS[mi][nf][r] * scale + ((nf * 16 + lm >= len) ? -1e9f : 0.f);
                accS[mi][nf][r] = s;
                mx = fmaxf(mx, s);
            }
#pragma unroll
            for (int off = 1; off < 16; off <<= 1) mx = fmaxf(mx, __shfl_xor(mx, off, 64));
            float sum = 0.f;
#pragma unroll
            for (int nf = 0; nf < 16; nf++) {
                float e = __expf(accS[mi][nf][r] - mx);
                accS[mi][nf][r] = e;
                sum += e;
            }
#pragma unroll
            for (int off = 1; off < 16; off <<= 1) sum += __shfl_xor(sum, off, 64);
            lrow[mi][r] = sum;
        }

    floatx4 accO[2][4];
#pragma unroll
    for (int mi = 0; mi < 2; mi++)
#pragma unroll
        for (int nj = 0; nj < 4; nj++) accO[mi][nj] = (floatx4){0.f, 0.f, 0.f, 0.f};

    unsigned short* sP = (unsigned short*)smem;
    const int rbase = wave * 32;
#pragma unroll
    for (int half = 0; half < 2; half++) {
        __syncthreads();
#pragma unroll
        for (int mi = 0; mi < 2; mi++)
#pragma unroll
            for (int nf2 = 0; nf2 < 8; nf2++) {
                int nf = half * 8 + nf2;
                int row = rbase + mi * 16 + quad * 4;
                int col = nf2 * 16 + lm;
#pragma unroll
                for (int r = 0; r < 4; r++)
                    sP[(row + r) * 136 + col] = f2bf(accS[mi][nf][r]);
            }
        __syncthreads();
#pragma unroll
        for (int ks2 = 0; ks2 < 4; ks2++) {
            bf16x8 ap[2];
#pragma unroll
            for (int mi = 0; mi < 2; mi++)
                ap[mi] = *(const bf16x8*)(sP + (rbase + mi * 16 + lm) * 136
                                          + ks2 * 32 + quad * 8);
            int ks = half * 4 + ks2;
#pragma unroll
            for (int nj = 0; nj < 4; nj++) {
                bf16x8 bv = *(const bf16x8*)(Vt + (size_t)(nj * 16 + lm) * 256
                                             + ks * 32 + quad * 8);
                accO[0][nj] = __builtin_amdgcn_mfma_f32_16x16x32_bf16(ap[0], bv, accO[0][nj], 0, 0, 0);
                accO[1][nj] = __builtin_amdgcn_mfma_f32_16x16x32_bf16(ap[1], bv, accO[1][nj], 0, 0, 0);
            }
        }
    }

#pragma unroll
    for (int mi = 0; mi < 2; mi++) {
        float inv[4];
#pragma unroll
        for (int r = 0; r < 4; r++) inv[r] = 1.f / lrow[mi][r];
        const int grow = b * 256 + qt * 128 + rbase + mi * 16 + quad * 4;
#pragma unroll
        for (int nj = 0; nj < 4; nj++) {
            const int gcol = h * 64 + nj * 16 + lm;
#pragma unroll
            for (int r = 0; r < 4; r++)
                o[(size_t)(grow + r) * 512 + gcol] = f2bf(accO[mi][nj][r] * inv[r]);
        }
    }
}

// ---------------------------------------------------------------------------
// x = LayerNorm(x + y_bf16) (y already has bias)
// ---------------------------------------------------------------------------
__global__ __launch_bounds__(128) void add_ln_bf16(
    unsigned short* __restrict__ x, const unsigned short* __restrict__ y,
    const float* __restrict__ s, const float* __restrict__ bb)
{
    __shared__ float red[2];
    const int row = blockIdx.x;
    const int tid = threadIdx.x;
    const int c = tid * 4;
    ushort4 xv = *(const ushort4*)(x + (size_t)row * D_ + c);
    ushort4 yv = *(const ushort4*)(y + (size_t)row * D_ + c);
    float h[4];
    h[0] = bf2f(xv.x) + bf2f(yv.x);
    h[1] = bf2f(xv.y) + bf2f(yv.y);
    h[2] = bf2f(xv.z) + bf2f(yv.z);
    h[3] = bf2f(xv.w) + bf2f(yv.w);

    float sum = h[0] + h[1] + h[2] + h[3];
#pragma unroll
    for (int off = 32; off >= 1; off >>= 1) sum += __shfl_xor(sum, off, 64);
    if ((tid & 63) == 0) red[tid >> 6] = sum;
    __syncthreads();
    float mean = (red[0] + red[1]) * (1.f / 512.f);
    __syncthreads();

    float d[4];
    d[0] = h[0] - mean; d[1] = h[1] - mean; d[2] = h[2] - mean; d[3] = h[3] - mean;
    float sq = d[0] * d[0] + d[1] * d[1] + d[2] * d[2] + d[3] * d[3];
#pragma unroll
    for (int off = 32; off >= 1; off >>= 1) sq += __shfl_xor(sq, off, 64);
    if ((tid & 63) == 0) red[tid >> 6] = sq;
    __syncthreads();
    float var = (red[0] + red[1]) * (1.f / 512.f);
    float rs = rsqrtf(var + 1e-5f);

    float4 sv = *(const float4*)(s + c);
    float4 bv = *(const float4*)(bb + c);
    ushort4 ov;
    ov.x = f2bf(d[0] * rs * sv.x + bv.x);
    ov.y = f2bf(d[1] * rs * sv.y + bv.y);
    ov.z = f2bf(d[2] * rs * sv.z + bv.z);
    ov.w = f2bf(d[3] * rs * sv.w + bv.w);
    *(ushort4*)(x + (size_t)row * D_ + c) = ov;
}

// ---------------------------------------------------------------------------
// x = LayerNorm(x + p0 + p1 + bias) (split-K partials, fp32); optional enc out
// ---------------------------------------------------------------------------
__global__ __launch_bounds__(128) void add_ln_part(
    unsigned short* __restrict__ x, const float* __restrict__ p0,
    const float* __restrict__ p1, const float* __restrict__ bias,
    const float* __restrict__ s, const float* __restrict__ bb,
    float* __restrict__ enc_opt)
{
    __shared__ float red[2];
    const int row = blockIdx.x;
    const int tid = threadIdx.x;
    const int c = tid * 4;
    ushort4 xv = *(const ushort4*)(x + (size_t)row * D_ + c);
    float4 a = *(const float4*)(p0 + (size_t)row * D_ + c);
    float4 bq = *(const float4*)(p1 + (size_t)row * D_ + c);
    float4 bi = *(const float4*)(bias + c);
    float h[4];
    h[0] = bf2f(xv.x) + a.x + bq.x + bi.x;
    h[1] = bf2f(xv.y) + a.y + bq.y + bi.y;
    h[2] = bf2f(xv.z) + a.z + bq.z + bi.z;
    h[3] = bf2f(xv.w) + a.w + bq.w + bi.w;

    float sum = h[0] + h[1] + h[2] + h[3];
#pragma unroll
    for (int off = 32; off >= 1; off >>= 1) sum += __shfl_xor(sum, off, 64);
    if ((tid & 63) == 0) red[tid >> 6] = sum;
    __syncthreads();
    float mean = (red[0] + red[1]) * (1.f / 512.f);
    __syncthreads();

    float d[4];
    d[0] = h[0] - mean; d[1] = h[1] - mean; d[2] = h[2] - mean; d[3] = h[3] - mean;
    float sq = d[0] * d[0] + d[1] * d[1] + d[2] * d[2] + d[3] * d[3];
#pragma unroll
    for (int off = 32; off >= 1; off >>= 1) sq += __shfl_xor(sq, off, 64);
    if ((tid & 63) == 0) red[tid >> 6] = sq;
    __syncthreads();
    float var = (red[0] + red[1]) * (1.f / 512.f);
    float rs = rsqrtf(var + 1e-5f);

    float4 sv = *(const float4*)(s + c);
    float4 bv = *(const float4*)(bb + c);
    float o[4];
    o[0] = d[0] * rs * sv.x + bv.x;
    o[1] = d[1] * rs * sv.y + bv.y;
    o[2] = d[2] * rs * sv.z + bv.z;
    o[3] = d[3] * rs * sv.w + bv.w;
    ushort4 ov;
    ov.x = f2bf(o[0]); ov.y = f2bf(o[1]); ov.z = f2bf(o[2]); ov.w = f2bf(o[3]);
    *(ushort4*)(x + (size_t)row * D_ + c) = ov;
    if (enc_opt) {
        float4 e; e.x = o[0]; e.y = o[1]; e.z = o[2]; e.w = o[3];
        *(float4*)(enc_opt + (size_t)row * D_ + c) = e;
    }
}

// ---------------------------------------------------------------------------
// Fused duration head: relu(p0+p1+b1).w2 + b2 -> softplus -> round/clamp ->
// block-wide cumsum. One block per batch, 1024 threads (16 waves).
// ---------------------------------------------------------------------------
__global__ __launch_bounds__(1024) void dur_head_fused(
    const float* __restrict__ p0, const float* __restrict__ p1,
    const float* __restrict__ b1, const float* __restrict__ w2,
    const float* __restrict__ b2, float* __restrict__ durout,
    int* __restrict__ cum)
{
    __shared__ int sd[256];
    const int tid = threadIdx.x;
    const int b = blockIdx.x;
    const int w = tid >> 6, lane = tid & 63;
    float4 bi = *(const float4*)(b1 + lane * 4);
    float4 wv = *(const float4*)(w2 + lane * 4);
#pragma unroll
    for (int it = 0; it < 16; it++) {
        const int s = it * 16 + w;
        const int r = b * 256 + s;
        float4 a = *(const float4*)(p0 + (size_t)r * 256 + lane * 4);
        float4 bq = *(const float4*)(p1 + (size_t)r * 256 + lane * 4);
        float h0 = fmaxf(a.x + bq.x + bi.x, 0.f);
        float h1 = fmaxf(a.y + bq.y + bi.y, 0.f);
        float h2 = fmaxf(a.z + bq.z + bi.z, 0.f);
        float h3 = fmaxf(a.w + bq.w + bi.w, 0.f);
        float p = h0 * wv.x + h1 * wv.y + h2 * wv.z + h3 * wv.w;
#pragma unroll
        for (int off = 32; off >= 1; off >>= 1) p += __shfl_xor(p, off, 64);
        if (lane == 0) {
            float v = p + b2[0];
            float dur = (v > 20.f) ? v : log1pf(expf(v));
            durout[r] = dur;
            int d = (int)rintf(dur);
            if (d < 1) d = 1;
            sd[s] = d;
        }
    }
    __syncthreads();
    // inclusive scan over sd[0..255]
    for (int off = 1; off < 256; off <<= 1) {
        int v = 0, add = 0;
        if (tid < 256) {
            v = sd[tid];
            add = (tid >= off) ? sd[tid - off] : 0;
        }
        __syncthreads();
        if (tid < 256) sd[tid] = v + add;
        __syncthreads();
    }
    if (tid < 256) cum[b * 256 + tid] = sd[tid];
}

// ---------------------------------------------------------------------------
// mel gather v2: LDS-staged rows (coalesced), coalesced writes.
// grid (T/256, 2 col-halves, B). mp = [4][4096][128] fp32 partials.
// ---------------------------------------------------------------------------
__global__ __launch_bounds__(256) void mel_gather2(
    const float* __restrict__ mp, const float* __restrict__ b2,
    const float* __restrict__ c0, const int* __restrict__ cum,
    float* __restrict__ mel_out)
{
    __shared__ float rows[256 * 40];
    __shared__ int sc[256];
    __shared__ float s0[40];
    const int tid = threadIdx.x;
    const int b = blockIdx.z;
    const int cc0 = blockIdx.y * 40;
    sc[tid] = cum[b * 256 + tid];
    if (tid < 40) s0[tid] = c0[cc0 + tid];
    const size_t plane = (size_t)M_ * 128;
    for (int idx = tid; idx < 256 * 40; idx += 256) {
        int r = idx / 40, c = idx - r * 40;
        size_t base = ((size_t)b * 256 + r) * 128 + cc0 + c;
        rows[idx] = mp[base] + mp[plane + base] + mp[2 * plane + base]
                  + mp[3 * plane + base] + b2[cc0 + c];
    }
    __syncthreads();
    const int total = sc[255];
    const int t = blockIdx.x * 256 + tid;
    int lo = 0, hi = 256;
    while (lo < hi) {
        int mid = (lo + hi) >> 1;
        if (sc[mid] <= t) lo = mid + 1; else hi = mid;
    }
    int row = lo < 255 ? lo : 255;
    const bool valid = t < total;
    const float* src = valid ? &rows[row * 40] : s0;
    for (int cc = 0; cc < 40; cc++)
        mel_out[((size_t)b * 80 + cc0 + cc) * T_ + t] = src[cc];
}

// ---------------------------------------------------------------------------
extern "C" void kernel_launch(void* const* d_in, const int* in_sizes, int n_in,
                              void* d_out, int out_size, void* d_ws, size_t ws_size,
                              hipStream_t stream)
{
    const int*   text_ids     = (const int*)d_in[0];
    const int*   text_lengths = (const int*)d_in[1];
    const float* emb   = (const float*)d_in[3];
    const float* pe    = (const float*)d_in[4];
    const float* Wqkv  = (const float*)d_in[5];
    const float* bqkv  = (const float*)d_in[6];
    const float* Wo    = (const float*)d_in[7];
    const float* bo    = (const float*)d_in[8];
    const float* ln1_s = (const float*)d_in[9];
    const float* ln1_b = (const float*)d_in[10];
    const float* ln2_s = (const float*)d_in[11];
    const float* ln2_b = (const float*)d_in[12];
    const float* W1    = (const float*)d_in[13];
    const float* b1    = (const float*)d_in[14];
    const float* W2    = (const float*)d_in[15];
    const float* b2    = (const float*)d_in[16];
    const float* mel_W1 = (const float*)d_in[17];
    const float* mel_b1 = (const float*)d_in[18];
    const float* mel_W2 = (const float*)d_in[19];
    const float* mel_b2 = (const float*)d_in[20];
    const float* dur_W1 = (const float*)d_in[21];
    const float* dur_b1 = (const float*)d_in[22];
    const float* dur_W2 = (const float*)d_in[23];
    const float* dur_b2 = (const float*)d_in[24];

    float* out = (float*)d_out;
    float* mel_out = out;
    float* dur_out = out + (size_t)B_ * NM_ * T_;
    float* enc_out = dur_out + (size_t)B_ * S_;

    typedef unsigned short u16;
    char* w = (char*)d_ws;
    u16* Wqkv_t  = (u16*)w;                   w += (size_t)L_ * 1536 * 512 * 2;
    u16* Wo_t    = (u16*)w;                   w += (size_t)L_ * 512 * 512 * 2;
    u16* W1_t    = (u16*)w;                   w += (size_t)L_ * 2048 * 512 * 2;
    u16* W2_t    = (u16*)w;                   w += (size_t)L_ * 512 * 2048 * 2;
    u16* melW1_t = (u16*)w;                   w += (size_t)2048 * 512 * 2;
    u16* melW2_t = (u16*)w;                   w += (size_t)128 * 2048 * 2;
    u16* durW1_t = (u16*)w;                   w += (size_t)256 * 512 * 2;
    u16* x_bf    = (u16*)w;                   w += (size_t)M_ * 512 * 2;
    u16* qkv_bf  = (u16*)w;                   w += (size_t)M_ * 1536 * 2;  // contiguous with
    u16* ao_bf   = (u16*)w;                   w += (size_t)M_ * 512 * 2;   // ao: 16.78MB union
    u16* y_bf    = (u16*)w;                   w += (size_t)M_ * 512 * 2;
    char* big    = w;                         w += (size_t)16777216;       // ffh/melh (+vt tail)
    float* c0    = (float*)w;                 w += 512;
    int*   cum   = (int*)w;                   w += (size_t)M_ * 4;

    u16* ffh     = (u16*)big;
    u16* melh    = (u16*)big;
    u16* vt      = (u16*)(big + 12582912);    // 4MB tail; disjoint from ffh lifetime

    float* part2 = (float*)qkv_bf;            // [2][4096][512] for FF2
    float* dpart = (float*)qkv_bf;            // [2][4096][256] for dur1
    float* mpart = (float*)(qkv_bf + (size_t)M_ * 512);  // [4][4096][128] for mel2

    // fused weight prep (all transposes + mel_c0): 19920 blocks
    prep_weights<<<19920, 256, 0, stream>>>(
        Wqkv, Wo, W1, W2, mel_W1, mel_W2, dur_W1, mel_b1, mel_b2,
        Wqkv_t, Wo_t, W1_t, W2_t, melW1_t, melW2_t, durW1_t, c0);

    embed_bf16<<<M_, 128, 0, stream>>>(text_ids, emb, pe, x_bf);

    for (int l = 0; l < L_; l++) {
        // QKV with fused V-transpose epilogue (V cols -> vt, Q/K cols -> qkv_bf)
        gemm2<128, 128><<<dim3(12, 32), 256, 0, stream>>>(
            x_bf, Wqkv_t + (size_t)l * 1536 * 512, bqkv + (size_t)l * 1536,
            qkv_bf, nullptr, vt, 1536, 512, 0);
        attn_fused<<<dim3(2, 128), 256, 0, stream>>>(qkv_bf, vt, text_lengths, ao_bf);
        gemm2<128, 64><<<dim3(8, 32), 256, 0, stream>>>(
            ao_bf, Wo_t + (size_t)l * 512 * 512, bo + (size_t)l * 512,
            y_bf, nullptr, nullptr, 512, 512, 0);
        add_ln_bf16<<<M_, 128, 0, stream>>>(
            x_bf, y_bf, ln1_s + (size_t)l * D_, ln1_b + (size_t)l * D_);
        gemm2<128, 128><<<dim3(16, 32), 256, 0, stream>>>(
            x_bf, W1_t + (size_t)l * 2048 * 512, b1 + (size_t)l * 2048,
            ffh, nullptr, nullptr, 2048, 512, 1);
        gemm2<128, 64><<<dim3(8, 32, 2), 256, 0, stream>>>(
            ffh, W2_t + (size_t)l * 512 * 2048, nullptr,
            nullptr, part2, nullptr, 512, 1024, 0);
        add_ln_part<<<M_, 128, 0, stream>>>(
            x_bf, part2, part2 + (size_t)M_ * 512, b2 + (size_t)l * 512,
            ln2_s + (size_t)l * D_, ln2_b + (size_t)l * D_,
            (l == L_ - 1) ? enc_out : nullptr);
    }

    // duration head (split-K=2 partials -> fused head+cumsum)
    gemm2<128, 64><<<dim3(4, 32, 2), 256, 0, stream>>>(
        x_bf, durW1_t, nullptr, nullptr, dpart, nullptr, 256, 256, 0);
    dur_head_fused<<<B_, 1024, 0, stream>>>(
        dpart, dpart + (size_t)M_ * 256, dur_b1, dur_W2, dur_b2, dur_out, cum);

    // mel head: mel1 (bf16, relu), mel2 (split-K=4 partials -> gather combines)
    gemm2<128, 128><<<dim3(16, 32), 256, 0, stream>>>(
        x_bf, melW1_t, mel_b1, melh, nullptr, nullptr, 2048, 512, 1);
    gemm2<128, 64><<<dim3(2, 32, 4), 256, 0, stream>>>(
        melh, melW2_t, nullptr, nullptr, mpart, nullptr, 128, 512, 0);
    mel_gather2<<<dim3(T_ / 256, 2, B_), 256, 0, stream>>>(mpart, mel_b2, c0, cum, mel_out);
}